// Round 5
// baseline (414.292 us; speedup 1.0000x reference)
//
#include <hip/hip_runtime.h>

#define N_NODES 100000
#define N_EDGES 1600000
#define IN_F 256
#define OUT_F 128

#define N4 (N_NODES / 4)               // 25000 int4 groups
#define SCAN_NB ((N4 + 255) / 256)     // 98 blocks
#define E4 (N_EDGES / 4)               // 400000 int4 edge groups

// ---------------- LDS-tiled GEMM: h[n][c] = (feat[n,:] @ W[:,c]) * cj[n] -----
#define BM 128
#define KC 32
#define FT_PAD 4

__global__ __launch_bounds__(256) void gemm_cj_kernel(const float* __restrict__ feat,
                                                      const float* __restrict__ W,
                                                      const float* __restrict__ cj,
                                                      float* __restrict__ h) {
    __shared__ float ft[KC][BM + FT_PAD];
    __shared__ float wt[KC][OUT_F];

    const int tid = threadIdx.x;
    const int tx = tid & 15;
    const int ty = tid >> 4;
    const int n_base = blockIdx.x * BM;

    const int s_row  = tid >> 3;
    const int s_koff = (tid & 7) * 4;

    float acc[8][8] = {};

    for (int kc = 0; kc < IN_F; kc += KC) {
        #pragma unroll
        for (int i = 0; i < 4; ++i) {
            int row = s_row + i * 32;
            int gn = n_base + row;
            if (gn >= N_NODES) gn = N_NODES - 1;
            float4 v = *reinterpret_cast<const float4*>(feat + (size_t)gn * IN_F + kc + s_koff);
            ft[s_koff + 0][row] = v.x;
            ft[s_koff + 1][row] = v.y;
            ft[s_koff + 2][row] = v.z;
            ft[s_koff + 3][row] = v.w;
        }
        const float4* Wc = reinterpret_cast<const float4*>(W + (size_t)kc * OUT_F);
        #pragma unroll
        for (int i = 0; i < 4; ++i) {
            int idx = tid + i * 256;
            float4 v = Wc[idx];
            *reinterpret_cast<float4*>(&wt[idx >> 5][(idx & 31) * 4]) = v;
        }
        __syncthreads();

        #pragma unroll 8
        for (int k = 0; k < KC; ++k) {
            float4 f0 = *reinterpret_cast<const float4*>(&ft[k][ty * 4]);
            float4 f1 = *reinterpret_cast<const float4*>(&ft[k][64 + ty * 4]);
            float4 w0 = *reinterpret_cast<const float4*>(&wt[k][tx * 4]);
            float4 w1 = *reinterpret_cast<const float4*>(&wt[k][64 + tx * 4]);
            float fv[8] = {f0.x, f0.y, f0.z, f0.w, f1.x, f1.y, f1.z, f1.w};
            float wv[8] = {w0.x, w0.y, w0.z, w0.w, w1.x, w1.y, w1.z, w1.w};
            #pragma unroll
            for (int i = 0; i < 8; ++i)
                #pragma unroll
                for (int j = 0; j < 8; ++j)
                    acc[i][j] = fmaf(fv[i], wv[j], acc[i][j]);
        }
        __syncthreads();
    }

    #pragma unroll
    for (int i = 0; i < 8; ++i) {
        int row = (i < 4) ? (ty * 4 + i) : (64 + ty * 4 + (i - 4));
        int gn = n_base + row;
        if (gn < N_NODES) {
            float s = cj[gn];
            float4 o0 = make_float4(acc[i][0] * s, acc[i][1] * s, acc[i][2] * s, acc[i][3] * s);
            float4 o1 = make_float4(acc[i][4] * s, acc[i][5] * s, acc[i][6] * s, acc[i][7] * s);
            float* hp = h + (size_t)gn * OUT_F;
            *reinterpret_cast<float4*>(hp + tx * 4) = o0;
            *reinterpret_cast<float4*>(hp + 64 + tx * 4) = o1;
        }
    }
}

// ---------------- CSR build ----------------
// 4 edges per thread: independent atomics overlap their L2 round-trips.
__global__ __launch_bounds__(256) void count_kernel(const int* __restrict__ dst,
                                                    int* __restrict__ cursor) {
    int t4 = blockIdx.x * 256 + threadIdx.x;
    if (t4 >= E4) return;
    int4 d = reinterpret_cast<const int4*>(dst)[t4];
    atomicAdd(&cursor[d.x], 1);
    atomicAdd(&cursor[d.y], 1);
    atomicAdd(&cursor[d.z], 1);
    atomicAdd(&cursor[d.w], 1);
}

// Multi-block exclusive scan of 100K counts, 3 phases.
__global__ __launch_bounds__(256) void scan_phaseA(const int* __restrict__ counts,
                                                   int* __restrict__ block_sums) {
    __shared__ int sdata[256];
    int t = threadIdx.x;
    int gi4 = blockIdx.x * 256 + t;
    int v = 0;
    if (gi4 < N4) {
        int4 x = reinterpret_cast<const int4*>(counts)[gi4];
        v = (x.x + x.y) + (x.z + x.w);
    }
    sdata[t] = v;
    __syncthreads();
    #pragma unroll
    for (int s = 128; s > 0; s >>= 1) {
        if (t < s) sdata[t] += sdata[t + s];
        __syncthreads();
    }
    if (t == 0) block_sums[blockIdx.x] = sdata[0];
}

__global__ __launch_bounds__(128) void scan_phaseB(int* __restrict__ block_sums) {
    __shared__ int sdata[128];
    int t = threadIdx.x;
    int v = (t < SCAN_NB) ? block_sums[t] : 0;
    sdata[t] = v;
    __syncthreads();
    #pragma unroll
    for (int off = 1; off < 128; off <<= 1) {
        int u = (t >= off) ? sdata[t - off] : 0;
        __syncthreads();
        sdata[t] += u;
        __syncthreads();
    }
    if (t < SCAN_NB) block_sums[t] = sdata[t] - v;
}

__global__ __launch_bounds__(256) void scan_phaseC(const int* __restrict__ block_sums,
                                                   int* __restrict__ offsets,
                                                   int* __restrict__ cursor) {
    __shared__ int sdata[256];
    int t = threadIdx.x;
    int gi4 = blockIdx.x * 256 + t;
    int4 x = make_int4(0, 0, 0, 0);
    bool valid = gi4 < N4;
    if (valid) x = reinterpret_cast<const int4*>(cursor)[gi4];
    int tot = (x.x + x.y) + (x.z + x.w);
    sdata[t] = tot;
    __syncthreads();
    #pragma unroll
    for (int off = 1; off < 256; off <<= 1) {
        int u = (t >= off) ? sdata[t - off] : 0;
        __syncthreads();
        sdata[t] += u;
        __syncthreads();
    }
    if (valid) {
        int base = block_sums[blockIdx.x] + sdata[t] - tot;
        int4 o;
        o.x = base;
        o.y = base + x.x;
        o.z = o.y + x.y;
        o.w = o.z + x.z;
        reinterpret_cast<int4*>(offsets)[gi4] = o;
        reinterpret_cast<int4*>(cursor)[gi4] = o;
    }
    if (blockIdx.x == 0 && t == 0) offsets[N_NODES] = N_EDGES;
}

// 4 edges per thread: 4 independent atomic chains + 4 independent stores.
__global__ __launch_bounds__(256) void fill_kernel(const int* __restrict__ src,
                                                   const int* __restrict__ dst,
                                                   int* __restrict__ cursor,
                                                   int* __restrict__ bin_src) {
    int t4 = blockIdx.x * 256 + threadIdx.x;
    if (t4 >= E4) return;
    int4 s = reinterpret_cast<const int4*>(src)[t4];
    int4 d = reinterpret_cast<const int4*>(dst)[t4];
    int p0 = atomicAdd(&cursor[d.x], 1);
    int p1 = atomicAdd(&cursor[d.y], 1);
    int p2 = atomicAdd(&cursor[d.z], 1);
    int p3 = atomicAdd(&cursor[d.w], 1);
    bin_src[p0] = s.x;
    bin_src[p1] = s.y;
    bin_src[p2] = s.z;
    bin_src[p3] = s.w;
}

// ---------------- Gather: out[d][c] = ci[d] * sum_{e in bin(d)} h[src_e][c] -----
__global__ __launch_bounds__(256) void gather_kernel(const float* __restrict__ h,
                                                     const float* __restrict__ ci,
                                                     const int* __restrict__ offsets,
                                                     const int* __restrict__ bin_src,
                                                     float* __restrict__ out) {
    int node = blockIdx.x * 8 + (threadIdx.x >> 5);
    int lane = threadIdx.x & 31;
    if (node >= N_NODES) return;

    int beg = offsets[node];
    int end = offsets[node + 1];
    const float4* h4 = reinterpret_cast<const float4*>(h);

    float4 acc = make_float4(0, 0, 0, 0);
    int i = beg;
    for (; i + 4 <= end; i += 4) {
        int s0 = bin_src[i + 0];
        int s1 = bin_src[i + 1];
        int s2 = bin_src[i + 2];
        int s3 = bin_src[i + 3];
        float4 v0 = h4[(size_t)s0 * 32 + lane];
        float4 v1 = h4[(size_t)s1 * 32 + lane];
        float4 v2 = h4[(size_t)s2 * 32 + lane];
        float4 v3 = h4[(size_t)s3 * 32 + lane];
        acc.x += (v0.x + v1.x) + (v2.x + v3.x);
        acc.y += (v0.y + v1.y) + (v2.y + v3.y);
        acc.z += (v0.z + v1.z) + (v2.z + v3.z);
        acc.w += (v0.w + v1.w) + (v2.w + v3.w);
    }
    for (; i < end; ++i) {
        int s = bin_src[i];
        float4 v = h4[(size_t)s * 32 + lane];
        acc.x += v.x; acc.y += v.y; acc.z += v.z; acc.w += v.w;
    }
    float sc = ci[node];
    acc.x *= sc; acc.y *= sc; acc.z *= sc; acc.w *= sc;
    reinterpret_cast<float4*>(out)[(size_t)node * 32 + lane] = acc;
}

extern "C" void kernel_launch(void* const* d_in, const int* in_sizes, int n_in,
                              void* d_out, int out_size, void* d_ws, size_t ws_size,
                              hipStream_t stream) {
    const float* feat = (const float*)d_in[0];
    const float* W    = (const float*)d_in[1];
    const float* cj   = (const float*)d_in[2];
    const float* ci   = (const float*)d_in[3];
    const int*   src  = (const int*)d_in[4];
    const int*   dst  = (const int*)d_in[5];
    float* out = (float*)d_out;

    const size_t H_BYTES   = (size_t)N_NODES * OUT_F * sizeof(float);
    const size_t OFF_BYTES = ((size_t)(N_NODES + 1) * sizeof(int) + 15) & ~(size_t)15;
    const size_t CUR_BYTES = (size_t)N_NODES * sizeof(int);
    const size_t BS_BYTES  = ((size_t)SCAN_NB * sizeof(int) + 15) & ~(size_t)15;

    char* ws = (char*)d_ws;
    float* h        = (float*)ws;   ws += H_BYTES;
    int* offsets    = (int*)ws;     ws += OFF_BYTES;
    int* cursor     = (int*)ws;     ws += CUR_BYTES;
    int* block_sums = (int*)ws;     ws += BS_BYTES;
    int* bin_src    = (int*)ws;

    gemm_cj_kernel<<<(N_NODES + BM - 1) / BM, 256, 0, stream>>>(feat, W, cj, h);

    hipMemsetAsync(cursor, 0, CUR_BYTES, stream);
    int e4blocks = (E4 + 255) / 256;
    count_kernel<<<e4blocks, 256, 0, stream>>>(dst, cursor);
    scan_phaseA<<<SCAN_NB, 256, 0, stream>>>(cursor, block_sums);
    scan_phaseB<<<1, 128, 0, stream>>>(block_sums);
    scan_phaseC<<<SCAN_NB, 256, 0, stream>>>(block_sums, offsets, cursor);
    fill_kernel<<<e4blocks, 256, 0, stream>>>(src, dst, cursor, bin_src);
    gather_kernel<<<(N_NODES + 7) / 8, 256, 0, stream>>>(h, ci, offsets, bin_src, out);
}

// Round 6
// 294.674 us; speedup vs baseline: 1.4059x; 1.4059x over previous
//
#include <hip/hip_runtime.h>

#define N_NODES 100000
#define N_EDGES 1600000
#define IN_F 256
#define OUT_F 128

#define N4 (N_NODES / 4)               // 25000 int4 groups
#define SCAN_NB ((N4 + 255) / 256)     // 98 blocks
#define E4 (N_EDGES / 4)               // 400000 int4 edge groups

#define BM 128
#define KC 32
#define FT_PAD 4

#define GEMM_BLOCKS ((N_NODES + BM - 1) / BM)      // 782
#define FILL_BLOCKS ((E4 + 255) / 256)             // 1563
#define FUSED_BLOCKS (GEMM_BLOCKS + FILL_BLOCKS)   // 2345

// ---- bf16 helpers (manual RNE pack/unpack; h is stored as bf16) ----
__device__ __forceinline__ unsigned int f2bf(float f) {
    unsigned int u = __float_as_uint(f);
    return (u + 0x7FFFu + ((u >> 16) & 1u)) >> 16;
}
__device__ __forceinline__ unsigned int pack2(float a, float b) {
    return f2bf(a) | (f2bf(b) << 16);
}
__device__ __forceinline__ float bf_lo(unsigned int u) { return __uint_as_float(u << 16); }
__device__ __forceinline__ float bf_hi(unsigned int u) { return __uint_as_float(u & 0xFFFF0000u); }

// ---------------- CSR build ----------------
__global__ __launch_bounds__(256) void count_kernel(const int* __restrict__ dst,
                                                    int* __restrict__ cursor) {
    int t4 = blockIdx.x * 256 + threadIdx.x;
    if (t4 >= E4) return;
    int4 d = reinterpret_cast<const int4*>(dst)[t4];
    atomicAdd(&cursor[d.x], 1);
    atomicAdd(&cursor[d.y], 1);
    atomicAdd(&cursor[d.z], 1);
    atomicAdd(&cursor[d.w], 1);
}

__global__ __launch_bounds__(256) void scan_phaseA(const int* __restrict__ counts,
                                                   int* __restrict__ block_sums) {
    __shared__ int sdata[256];
    int t = threadIdx.x;
    int gi4 = blockIdx.x * 256 + t;
    int v = 0;
    if (gi4 < N4) {
        int4 x = reinterpret_cast<const int4*>(counts)[gi4];
        v = (x.x + x.y) + (x.z + x.w);
    }
    sdata[t] = v;
    __syncthreads();
    #pragma unroll
    for (int s = 128; s > 0; s >>= 1) {
        if (t < s) sdata[t] += sdata[t + s];
        __syncthreads();
    }
    if (t == 0) block_sums[blockIdx.x] = sdata[0];
}

__global__ __launch_bounds__(128) void scan_phaseB(int* __restrict__ block_sums) {
    __shared__ int sdata[128];
    int t = threadIdx.x;
    int v = (t < SCAN_NB) ? block_sums[t] : 0;
    sdata[t] = v;
    __syncthreads();
    #pragma unroll
    for (int off = 1; off < 128; off <<= 1) {
        int u = (t >= off) ? sdata[t - off] : 0;
        __syncthreads();
        sdata[t] += u;
        __syncthreads();
    }
    if (t < SCAN_NB) block_sums[t] = sdata[t] - v;
}

__global__ __launch_bounds__(256) void scan_phaseC(const int* __restrict__ block_sums,
                                                   int* __restrict__ offsets,
                                                   int* __restrict__ cursor) {
    __shared__ int sdata[256];
    int t = threadIdx.x;
    int gi4 = blockIdx.x * 256 + t;
    int4 x = make_int4(0, 0, 0, 0);
    bool valid = gi4 < N4;
    if (valid) x = reinterpret_cast<const int4*>(cursor)[gi4];
    int tot = (x.x + x.y) + (x.z + x.w);
    sdata[t] = tot;
    __syncthreads();
    #pragma unroll
    for (int off = 1; off < 256; off <<= 1) {
        int u = (t >= off) ? sdata[t - off] : 0;
        __syncthreads();
        sdata[t] += u;
        __syncthreads();
    }
    if (valid) {
        int base = block_sums[blockIdx.x] + sdata[t] - tot;
        int4 o;
        o.x = base;
        o.y = base + x.x;
        o.z = o.y + x.y;
        o.w = o.z + x.z;
        reinterpret_cast<int4*>(offsets)[gi4] = o;
        reinterpret_cast<int4*>(cursor)[gi4] = o;
    }
    if (blockIdx.x == 0 && t == 0) offsets[N_NODES] = N_EDGES;
}

// ---------------- Fused kernel: gemm tiles (bid%3==0) + fill chunks (else) -----
// gemm: h_bf16[n][c] = bf16( (feat[n,:] @ W[:,c]) * cj[n] )
// fill: bin_src[atomic cursor[dst]] = src  (4 edges/thread)
__global__ __launch_bounds__(256) void gemm_fill_kernel(const float* __restrict__ feat,
                                                        const float* __restrict__ W,
                                                        const float* __restrict__ cj,
                                                        unsigned int* __restrict__ h,   // bf16 pairs
                                                        const int* __restrict__ src,
                                                        const int* __restrict__ dst,
                                                        int* __restrict__ cursor,
                                                        int* __restrict__ bin_src) {
    __shared__ float ft[KC][BM + FT_PAD];
    __shared__ float wt[KC][OUT_F];

    const int bid = blockIdx.x;
    const int tid = threadIdx.x;

    if (bid % 3 != 0) {
        // ---- fill role ----
        int fid = bid - (bid + 2) / 3;           // 0..FILL_BLOCKS-1
        int t4 = fid * 256 + tid;
        if (t4 >= E4) return;
        int4 s = reinterpret_cast<const int4*>(src)[t4];
        int4 d = reinterpret_cast<const int4*>(dst)[t4];
        int p0 = atomicAdd(&cursor[d.x], 1);
        int p1 = atomicAdd(&cursor[d.y], 1);
        int p2 = atomicAdd(&cursor[d.z], 1);
        int p3 = atomicAdd(&cursor[d.w], 1);
        bin_src[p0] = s.x;
        bin_src[p1] = s.y;
        bin_src[p2] = s.z;
        bin_src[p3] = s.w;
        return;
    }

    // ---- gemm role ----
    const int gid = bid / 3;                     // 0..GEMM_BLOCKS-1
    const int tx = tid & 15;
    const int ty = tid >> 4;
    const int n_base = gid * BM;

    const int s_row  = tid >> 3;
    const int s_koff = (tid & 7) * 4;

    float acc[8][8] = {};

    for (int kc = 0; kc < IN_F; kc += KC) {
        #pragma unroll
        for (int i = 0; i < 4; ++i) {
            int row = s_row + i * 32;
            int gn = n_base + row;
            if (gn >= N_NODES) gn = N_NODES - 1;
            float4 v = *reinterpret_cast<const float4*>(feat + (size_t)gn * IN_F + kc + s_koff);
            ft[s_koff + 0][row] = v.x;
            ft[s_koff + 1][row] = v.y;
            ft[s_koff + 2][row] = v.z;
            ft[s_koff + 3][row] = v.w;
        }
        const float4* Wc = reinterpret_cast<const float4*>(W + (size_t)kc * OUT_F);
        #pragma unroll
        for (int i = 0; i < 4; ++i) {
            int idx = tid + i * 256;
            float4 v = Wc[idx];
            *reinterpret_cast<float4*>(&wt[idx >> 5][(idx & 31) * 4]) = v;
        }
        __syncthreads();

        #pragma unroll 8
        for (int k = 0; k < KC; ++k) {
            float4 f0 = *reinterpret_cast<const float4*>(&ft[k][ty * 4]);
            float4 f1 = *reinterpret_cast<const float4*>(&ft[k][64 + ty * 4]);
            float4 w0 = *reinterpret_cast<const float4*>(&wt[k][tx * 4]);
            float4 w1 = *reinterpret_cast<const float4*>(&wt[k][64 + tx * 4]);
            float fv[8] = {f0.x, f0.y, f0.z, f0.w, f1.x, f1.y, f1.z, f1.w};
            float wv[8] = {w0.x, w0.y, w0.z, w0.w, w1.x, w1.y, w1.z, w1.w};
            #pragma unroll
            for (int i = 0; i < 8; ++i)
                #pragma unroll
                for (int j = 0; j < 8; ++j)
                    acc[i][j] = fmaf(fv[i], wv[j], acc[i][j]);
        }
        __syncthreads();
    }

    #pragma unroll
    for (int i = 0; i < 8; ++i) {
        int row = (i < 4) ? (ty * 4 + i) : (64 + ty * 4 + (i - 4));
        int gn = n_base + row;
        if (gn < N_NODES) {
            float s = cj[gn];
            uint2 o0, o1;
            o0.x = pack2(acc[i][0] * s, acc[i][1] * s);
            o0.y = pack2(acc[i][2] * s, acc[i][3] * s);
            o1.x = pack2(acc[i][4] * s, acc[i][5] * s);
            o1.y = pack2(acc[i][6] * s, acc[i][7] * s);
            uint2* hp = reinterpret_cast<uint2*>(h) + (size_t)gn * 32;
            hp[tx]      = o0;    // cols tx*4..tx*4+3
            hp[16 + tx] = o1;    // cols 64+tx*4..64+tx*4+3
        }
    }
}

// ---------------- Gather: out[d][c] = ci[d] * sum_{e in bin(d)} h_bf16[src_e][c] --
// 32 lanes per node, uint2 (4 bf16) per lane; 4 source rows in flight.
__global__ __launch_bounds__(256) void gather_kernel(const unsigned int* __restrict__ h,
                                                     const float* __restrict__ ci,
                                                     const int* __restrict__ offsets,
                                                     const int* __restrict__ bin_src,
                                                     float* __restrict__ out) {
    int node = blockIdx.x * 8 + (threadIdx.x >> 5);
    int lane = threadIdx.x & 31;
    if (node >= N_NODES) return;

    int beg = offsets[node];
    int end = offsets[node + 1];
    const uint2* h2 = reinterpret_cast<const uint2*>(h);

    float4 acc = make_float4(0, 0, 0, 0);
    int i = beg;
    for (; i + 4 <= end; i += 4) {
        int s0 = bin_src[i + 0];
        int s1 = bin_src[i + 1];
        int s2 = bin_src[i + 2];
        int s3 = bin_src[i + 3];
        uint2 v0 = h2[(size_t)s0 * 32 + lane];
        uint2 v1 = h2[(size_t)s1 * 32 + lane];
        uint2 v2 = h2[(size_t)s2 * 32 + lane];
        uint2 v3 = h2[(size_t)s3 * 32 + lane];
        acc.x += (bf_lo(v0.x) + bf_lo(v1.x)) + (bf_lo(v2.x) + bf_lo(v3.x));
        acc.y += (bf_hi(v0.x) + bf_hi(v1.x)) + (bf_hi(v2.x) + bf_hi(v3.x));
        acc.z += (bf_lo(v0.y) + bf_lo(v1.y)) + (bf_lo(v2.y) + bf_lo(v3.y));
        acc.w += (bf_hi(v0.y) + bf_hi(v1.y)) + (bf_hi(v2.y) + bf_hi(v3.y));
    }
    for (; i < end; ++i) {
        int s = bin_src[i];
        uint2 v = h2[(size_t)s * 32 + lane];
        acc.x += bf_lo(v.x);
        acc.y += bf_hi(v.x);
        acc.z += bf_lo(v.y);
        acc.w += bf_hi(v.y);
    }
    float sc = ci[node];
    acc.x *= sc; acc.y *= sc; acc.z *= sc; acc.w *= sc;
    reinterpret_cast<float4*>(out)[(size_t)node * 32 + lane] = acc;
}

extern "C" void kernel_launch(void* const* d_in, const int* in_sizes, int n_in,
                              void* d_out, int out_size, void* d_ws, size_t ws_size,
                              hipStream_t stream) {
    const float* feat = (const float*)d_in[0];
    const float* W    = (const float*)d_in[1];
    const float* cj   = (const float*)d_in[2];
    const float* ci   = (const float*)d_in[3];
    const int*   src  = (const int*)d_in[4];
    const int*   dst  = (const int*)d_in[5];
    float* out = (float*)d_out;

    const size_t H_BYTES   = (size_t)N_NODES * OUT_F * 2;   // bf16 h = 25.6 MB
    const size_t OFF_BYTES = ((size_t)(N_NODES + 1) * sizeof(int) + 15) & ~(size_t)15;
    const size_t CUR_BYTES = (size_t)N_NODES * sizeof(int);
    const size_t BS_BYTES  = ((size_t)SCAN_NB * sizeof(int) + 15) & ~(size_t)15;

    char* ws = (char*)d_ws;
    unsigned int* h = (unsigned int*)ws;  ws += H_BYTES;
    int* offsets    = (int*)ws;           ws += OFF_BYTES;
    int* cursor     = (int*)ws;           ws += CUR_BYTES;
    int* block_sums = (int*)ws;           ws += BS_BYTES;
    int* bin_src    = (int*)ws;

    // CSR chain first (independent of GEMM), so fill can fuse with gemm.
    hipMemsetAsync(cursor, 0, CUR_BYTES, stream);
    count_kernel<<<FILL_BLOCKS, 256, 0, stream>>>(dst, cursor);
    scan_phaseA<<<SCAN_NB, 256, 0, stream>>>(cursor, block_sums);
    scan_phaseB<<<1, 128, 0, stream>>>(block_sums);
    scan_phaseC<<<SCAN_NB, 256, 0, stream>>>(block_sums, offsets, cursor);

    gemm_fill_kernel<<<FUSED_BLOCKS, 256, 0, stream>>>(feat, W, cj, h, src, dst, cursor, bin_src);

    gather_kernel<<<(N_NODES + 7) / 8, 256, 0, stream>>>(h, ci, offsets, bin_src, out);
}

// Round 7
// 282.297 us; speedup vs baseline: 1.4676x; 1.0438x over previous
//
#include <hip/hip_runtime.h>

#define N_NODES 100000
#define N_EDGES 1600000
#define IN_F 256
#define OUT_F 128

#define N4 (N_NODES / 4)               // 25000 int4 groups
#define SCAN_NB ((N4 + 255) / 256)     // 98 blocks
#define E4 (N_EDGES / 4)               // 400000 int4 edge groups

#define BM 128
#define KC 32
#define FT_PAD 4

#define XCDS 8
#define NODES_PER_XCD (N_NODES / XCDS) // 12500

#define GEMM_BLOCKS ((N_NODES + BM - 1) / BM)      // 782
// fused grid: per-XCD sequence k=0..293; k%3==0 -> gemm (98/xcd, 784 total >= 782),
// else fill rank r=0..195 (196 ranks per xcd group)
#define K_PER_XCD 294
#define FILL_RANKS 196
#define FUSED_BLOCKS (XCDS * K_PER_XCD)            // 2352

// ---- bf16 helpers (manual RNE pack/unpack; h is stored as bf16) ----
__device__ __forceinline__ unsigned int f2bf(float f) {
    unsigned int u = __float_as_uint(f);
    return (u + 0x7FFFu + ((u >> 16) & 1u)) >> 16;
}
__device__ __forceinline__ unsigned int pack2(float a, float b) {
    return f2bf(a) | (f2bf(b) << 16);
}
__device__ __forceinline__ float bf_lo(unsigned int u) { return __uint_as_float(u << 16); }
__device__ __forceinline__ float bf_hi(unsigned int u) { return __uint_as_float(u & 0xFFFF0000u); }

// ---------------- CSR build ----------------
__global__ __launch_bounds__(256) void count_kernel(const int* __restrict__ dst,
                                                    int* __restrict__ cursor) {
    int t4 = blockIdx.x * 256 + threadIdx.x;
    if (t4 >= E4) return;
    int4 d = reinterpret_cast<const int4*>(dst)[t4];
    atomicAdd(&cursor[d.x], 1);
    atomicAdd(&cursor[d.y], 1);
    atomicAdd(&cursor[d.z], 1);
    atomicAdd(&cursor[d.w], 1);
}

__global__ __launch_bounds__(256) void scan_phaseA(const int* __restrict__ counts,
                                                   int* __restrict__ block_sums) {
    __shared__ int sdata[256];
    int t = threadIdx.x;
    int gi4 = blockIdx.x * 256 + t;
    int v = 0;
    if (gi4 < N4) {
        int4 x = reinterpret_cast<const int4*>(counts)[gi4];
        v = (x.x + x.y) + (x.z + x.w);
    }
    sdata[t] = v;
    __syncthreads();
    #pragma unroll
    for (int s = 128; s > 0; s >>= 1) {
        if (t < s) sdata[t] += sdata[t + s];
        __syncthreads();
    }
    if (t == 0) block_sums[blockIdx.x] = sdata[0];
}

__global__ __launch_bounds__(128) void scan_phaseB(int* __restrict__ block_sums) {
    __shared__ int sdata[128];
    int t = threadIdx.x;
    int v = (t < SCAN_NB) ? block_sums[t] : 0;
    sdata[t] = v;
    __syncthreads();
    #pragma unroll
    for (int off = 1; off < 128; off <<= 1) {
        int u = (t >= off) ? sdata[t - off] : 0;
        __syncthreads();
        sdata[t] += u;
        __syncthreads();
    }
    if (t < SCAN_NB) block_sums[t] = sdata[t] - v;
}

__global__ __launch_bounds__(256) void scan_phaseC(const int* __restrict__ block_sums,
                                                   int* __restrict__ offsets,
                                                   int* __restrict__ cursor) {
    __shared__ int sdata[256];
    int t = threadIdx.x;
    int gi4 = blockIdx.x * 256 + t;
    int4 x = make_int4(0, 0, 0, 0);
    bool valid = gi4 < N4;
    if (valid) x = reinterpret_cast<const int4*>(cursor)[gi4];
    int tot = (x.x + x.y) + (x.z + x.w);
    sdata[t] = tot;
    __syncthreads();
    #pragma unroll
    for (int off = 1; off < 256; off <<= 1) {
        int u = (t >= off) ? sdata[t - off] : 0;
        __syncthreads();
        sdata[t] += u;
        __syncthreads();
    }
    if (valid) {
        int base = block_sums[blockIdx.x] + sdata[t] - tot;
        int4 o;
        o.x = base;
        o.y = base + x.x;
        o.z = o.y + x.y;
        o.w = o.z + x.z;
        reinterpret_cast<int4*>(offsets)[gi4] = o;
        reinterpret_cast<int4*>(cursor)[gi4] = o;
    }
    if (blockIdx.x == 0 && t == 0) offsets[N_NODES] = N_EDGES;
}

// ---------------- Fused: gemm tiles + XCD-grouped fill ----------------
// Blocks are split per presumed-XCD (bid&7). Within each XCD's round-robin
// sequence k=bid>>3: k%3==0 -> gemm tile, else fill rank. Fill group x owns
// node range [x*12500,(x+1)*12500): it scans ALL edges, filters dst into its
// range, so every bin_src line is written from ONE XCD's L2 (no line bounce).
__global__ __launch_bounds__(256) void gemm_fill_kernel(const float* __restrict__ feat,
                                                        const float* __restrict__ W,
                                                        const float* __restrict__ cj,
                                                        unsigned int* __restrict__ h,   // bf16 pairs
                                                        const int* __restrict__ src,
                                                        const int* __restrict__ dst,
                                                        int* __restrict__ cursor,
                                                        int* __restrict__ bin_src) {
    __shared__ float ft[KC][BM + FT_PAD];
    __shared__ float wt[KC][OUT_F];

    const int bid = blockIdx.x;
    const int tid = threadIdx.x;
    const int x = bid & 7;        // presumed XCD
    const int k = bid >> 3;

    if (k % 3 != 0) {
        // ---- fill role: rank within this XCD group ----
        const int r = k - k / 3 - 1;              // 0..FILL_RANKS-1
        const int nlo = x * NODES_PER_XCD;
        const int nhi = nlo + NODES_PER_XCD;
        const int4* s4 = reinterpret_cast<const int4*>(src);
        const int4* d4 = reinterpret_cast<const int4*>(dst);
        const int stride = FILL_RANKS * 256;
        for (int t4 = r * 256 + tid; t4 < E4; t4 += stride) {
            int4 d = d4[t4];
            bool i0 = (d.x >= nlo) & (d.x < nhi);
            bool i1 = (d.y >= nlo) & (d.y < nhi);
            bool i2 = (d.z >= nlo) & (d.z < nhi);
            bool i3 = (d.w >= nlo) & (d.w < nhi);
            if (!(i0 | i1 | i2 | i3)) continue;
            int4 s = s4[t4];
            if (i0) { int p = atomicAdd(&cursor[d.x], 1); bin_src[p] = s.x; }
            if (i1) { int p = atomicAdd(&cursor[d.y], 1); bin_src[p] = s.y; }
            if (i2) { int p = atomicAdd(&cursor[d.z], 1); bin_src[p] = s.z; }
            if (i3) { int p = atomicAdd(&cursor[d.w], 1); bin_src[p] = s.w; }
        }
        return;
    }

    // ---- gemm role ----
    const int gid = (k / 3) * 8 + x;
    if (gid >= GEMM_BLOCKS) return;
    const int tx = tid & 15;
    const int ty = tid >> 4;
    const int n_base = gid * BM;

    const int s_row  = tid >> 3;
    const int s_koff = (tid & 7) * 4;

    float acc[8][8] = {};

    for (int kc = 0; kc < IN_F; kc += KC) {
        #pragma unroll
        for (int i = 0; i < 4; ++i) {
            int row = s_row + i * 32;
            int gn = n_base + row;
            if (gn >= N_NODES) gn = N_NODES - 1;
            float4 v = *reinterpret_cast<const float4*>(feat + (size_t)gn * IN_F + kc + s_koff);
            ft[s_koff + 0][row] = v.x;
            ft[s_koff + 1][row] = v.y;
            ft[s_koff + 2][row] = v.z;
            ft[s_koff + 3][row] = v.w;
        }
        const float4* Wc = reinterpret_cast<const float4*>(W + (size_t)kc * OUT_F);
        #pragma unroll
        for (int i = 0; i < 4; ++i) {
            int idx = tid + i * 256;
            float4 v = Wc[idx];
            *reinterpret_cast<float4*>(&wt[idx >> 5][(idx & 31) * 4]) = v;
        }
        __syncthreads();

        #pragma unroll 8
        for (int kk = 0; kk < KC; ++kk) {
            float4 f0 = *reinterpret_cast<const float4*>(&ft[kk][ty * 4]);
            float4 f1 = *reinterpret_cast<const float4*>(&ft[kk][64 + ty * 4]);
            float4 w0 = *reinterpret_cast<const float4*>(&wt[kk][tx * 4]);
            float4 w1 = *reinterpret_cast<const float4*>(&wt[kk][64 + tx * 4]);
            float fv[8] = {f0.x, f0.y, f0.z, f0.w, f1.x, f1.y, f1.z, f1.w};
            float wv[8] = {w0.x, w0.y, w0.z, w0.w, w1.x, w1.y, w1.z, w1.w};
            #pragma unroll
            for (int i = 0; i < 8; ++i)
                #pragma unroll
                for (int j = 0; j < 8; ++j)
                    acc[i][j] = fmaf(fv[i], wv[j], acc[i][j]);
        }
        __syncthreads();
    }

    #pragma unroll
    for (int i = 0; i < 8; ++i) {
        int row = (i < 4) ? (ty * 4 + i) : (64 + ty * 4 + (i - 4));
        int gn = n_base + row;
        if (gn < N_NODES) {
            float s = cj[gn];
            uint2 o0, o1;
            o0.x = pack2(acc[i][0] * s, acc[i][1] * s);
            o0.y = pack2(acc[i][2] * s, acc[i][3] * s);
            o1.x = pack2(acc[i][4] * s, acc[i][5] * s);
            o1.y = pack2(acc[i][6] * s, acc[i][7] * s);
            uint2* hp = reinterpret_cast<uint2*>(h) + (size_t)gn * 32;
            hp[tx]      = o0;
            hp[16 + tx] = o1;
        }
    }
}

// ---------------- Gather: out[d][c] = ci[d] * sum_{e in bin(d)} h_bf16[src_e][c] --
__global__ __launch_bounds__(256) void gather_kernel(const unsigned int* __restrict__ h,
                                                     const float* __restrict__ ci,
                                                     const int* __restrict__ offsets,
                                                     const int* __restrict__ bin_src,
                                                     float* __restrict__ out) {
    int node = blockIdx.x * 8 + (threadIdx.x >> 5);
    int lane = threadIdx.x & 31;
    if (node >= N_NODES) return;

    int beg = offsets[node];
    int end = offsets[node + 1];
    const uint2* h2 = reinterpret_cast<const uint2*>(h);

    float4 acc = make_float4(0, 0, 0, 0);
    int i = beg;
    for (; i + 4 <= end; i += 4) {
        int s0 = bin_src[i + 0];
        int s1 = bin_src[i + 1];
        int s2 = bin_src[i + 2];
        int s3 = bin_src[i + 3];
        uint2 v0 = h2[(size_t)s0 * 32 + lane];
        uint2 v1 = h2[(size_t)s1 * 32 + lane];
        uint2 v2 = h2[(size_t)s2 * 32 + lane];
        uint2 v3 = h2[(size_t)s3 * 32 + lane];
        acc.x += (bf_lo(v0.x) + bf_lo(v1.x)) + (bf_lo(v2.x) + bf_lo(v3.x));
        acc.y += (bf_hi(v0.x) + bf_hi(v1.x)) + (bf_hi(v2.x) + bf_hi(v3.x));
        acc.z += (bf_lo(v0.y) + bf_lo(v1.y)) + (bf_lo(v2.y) + bf_lo(v3.y));
        acc.w += (bf_hi(v0.y) + bf_hi(v1.y)) + (bf_hi(v2.y) + bf_hi(v3.y));
    }
    for (; i < end; ++i) {
        int s = bin_src[i];
        uint2 v = h2[(size_t)s * 32 + lane];
        acc.x += bf_lo(v.x);
        acc.y += bf_hi(v.x);
        acc.z += bf_lo(v.y);
        acc.w += bf_hi(v.y);
    }
    float sc = ci[node];
    acc.x *= sc; acc.y *= sc; acc.z *= sc; acc.w *= sc;
    reinterpret_cast<float4*>(out)[(size_t)node * 32 + lane] = acc;
}

extern "C" void kernel_launch(void* const* d_in, const int* in_sizes, int n_in,
                              void* d_out, int out_size, void* d_ws, size_t ws_size,
                              hipStream_t stream) {
    const float* feat = (const float*)d_in[0];
    const float* W    = (const float*)d_in[1];
    const float* cj   = (const float*)d_in[2];
    const float* ci   = (const float*)d_in[3];
    const int*   src  = (const int*)d_in[4];
    const int*   dst  = (const int*)d_in[5];
    float* out = (float*)d_out;

    const size_t H_BYTES   = (size_t)N_NODES * OUT_F * 2;   // bf16 h = 25.6 MB
    const size_t OFF_BYTES = ((size_t)(N_NODES + 1) * sizeof(int) + 15) & ~(size_t)15;
    const size_t CUR_BYTES = (size_t)N_NODES * sizeof(int);
    const size_t BS_BYTES  = ((size_t)SCAN_NB * sizeof(int) + 15) & ~(size_t)15;

    char* ws = (char*)d_ws;
    unsigned int* h = (unsigned int*)ws;  ws += H_BYTES;
    int* offsets    = (int*)ws;           ws += OFF_BYTES;
    int* cursor     = (int*)ws;           ws += CUR_BYTES;
    int* block_sums = (int*)ws;           ws += BS_BYTES;
    int* bin_src    = (int*)ws;

    // CSR chain first (independent of GEMM), so fill can fuse with gemm.
    hipMemsetAsync(cursor, 0, CUR_BYTES, stream);
    count_kernel<<<(E4 + 255) / 256, 256, 0, stream>>>(dst, cursor);
    scan_phaseA<<<SCAN_NB, 256, 0, stream>>>(cursor, block_sums);
    scan_phaseB<<<1, 128, 0, stream>>>(block_sums);
    scan_phaseC<<<SCAN_NB, 256, 0, stream>>>(block_sums, offsets, cursor);

    gemm_fill_kernel<<<FUSED_BLOCKS, 256, 0, stream>>>(feat, W, cj, h, src, dst, cursor, bin_src);

    gather_kernel<<<(N_NODES + 7) / 8, 256, 0, stream>>>(h, ci, offsets, bin_src, out);
}

// Round 8
// 226.595 us; speedup vs baseline: 1.8283x; 1.2458x over previous
//
#include <hip/hip_runtime.h>

#define N_NODES 100000
#define N_EDGES 1600000
#define IN_F 256
#define OUT_F 128

#define N4 (N_NODES / 4)               // 25000
#define SCAN_NB ((N4 + 255) / 256)     // 98
#define E4 (N_EDGES / 4)               // 400000

#define BUCKETS 256
#define NPB 391                        // 256*391 = 100096 >= N_NODES
#define CH 4096                        // edges per partition chunk
#define NCHUNK ((N_EDGES + CH - 1) / CH)   // 391

#define GEMM_BLOCKS ((N_NODES + 63) / 64)  // 1563 (64 rows/block, 4 waves x 16)
#define GC_BLOCKS (GEMM_BLOCKS + NCHUNK)   // + 391 count blocks

typedef short bf16x8 __attribute__((ext_vector_type(8)));
typedef float f32x4 __attribute__((ext_vector_type(4)));

// ---- bf16 helpers (RNE) ----
__device__ __forceinline__ unsigned int f2bf(float f) {
    unsigned int u = __float_as_uint(f);
    return (u + 0x7FFFu + ((u >> 16) & 1u)) >> 16;
}
__device__ __forceinline__ unsigned int pack2(float a, float b) {
    return f2bf(a) | (f2bf(b) << 16);
}
__device__ __forceinline__ float bf_lo(unsigned int u) { return __uint_as_float(u << 16); }
__device__ __forceinline__ float bf_hi(unsigned int u) { return __uint_as_float(u & 0xFFFF0000u); }

// ---------------- W transpose + bf16: Wt[n][k] = bf16(W[k][n]) ----------------
__global__ __launch_bounds__(256) void wprep_kernel(const float* __restrict__ W,
                                                    unsigned short* __restrict__ Wt) {
    int idx = blockIdx.x * 256 + threadIdx.x;       // 32768 total
    if (idx < IN_F * OUT_F) {
        int n = idx >> 8;        // /256
        int k = idx & 255;
        Wt[idx] = (unsigned short)f2bf(W[k * OUT_F + n]);
    }
}

// ---------------- Fused: MFMA gemm (h = bf16((feat@W)*cj)) + degree count -----
// gemm role: 64 rows/block, wave w -> rows base+w*16..+15; per wave 8 col-frags.
// count role: 391 blocks x 4096 edges, global atomics on counts[].
__global__ __launch_bounds__(256) void gemm_count_kernel(const float* __restrict__ feat,
                                                         const unsigned short* __restrict__ Wt,
                                                         const float* __restrict__ cj,
                                                         unsigned short* __restrict__ h,
                                                         const int* __restrict__ dst,
                                                         int* __restrict__ counts) {
    const int bid = blockIdx.x;
    const int tid = threadIdx.x;

    if (bid >= GEMM_BLOCKS) {
        // ---- count role ----
        int cb = bid - GEMM_BLOCKS;
        const int4* d4 = reinterpret_cast<const int4*>(dst);
        #pragma unroll
        for (int i = 0; i < 4; ++i) {
            int g4 = cb * 1024 + tid + i * 256;
            if (g4 < E4) {
                int4 d = d4[g4];
                atomicAdd(&counts[d.x], 1);
                atomicAdd(&counts[d.y], 1);
                atomicAdd(&counts[d.z], 1);
                atomicAdd(&counts[d.w], 1);
            }
        }
        return;
    }

    // ---- gemm role ----
    const int wave = tid >> 6;
    const int lane = tid & 63;
    const int rowbase = bid * 64 + wave * 16;
    const int r  = lane & 15;
    const int kq = lane >> 4;

    int arow = rowbase + r;
    if (arow >= N_NODES) arow = N_NODES - 1;
    const float* fr = feat + (size_t)arow * IN_F;

    f32x4 acc[8];
    #pragma unroll
    for (int f = 0; f < 8; ++f) acc[f] = (f32x4){0.f, 0.f, 0.f, 0.f};

    #pragma unroll
    for (int kt = 0; kt < 8; ++kt) {
        int k0 = kt * 32 + kq * 8;
        float4 fa = *reinterpret_cast<const float4*>(fr + k0);
        float4 fb = *reinterpret_cast<const float4*>(fr + k0 + 4);
        uint4 au;
        au.x = pack2(fa.x, fa.y);
        au.y = pack2(fa.z, fa.w);
        au.z = pack2(fb.x, fb.y);
        au.w = pack2(fb.z, fb.w);
        bf16x8 a = *reinterpret_cast<bf16x8*>(&au);
        #pragma unroll
        for (int f = 0; f < 8; ++f) {
            int c = f * 16 + r;
            bf16x8 b = *reinterpret_cast<const bf16x8*>(Wt + c * IN_F + k0);
            acc[f] = __builtin_amdgcn_mfma_f32_16x16x32_bf16(a, b, acc[f], 0, 0, 0);
        }
    }

    // epilogue: C/D layout col = lane&15, row = (lane>>4)*4 + reg
    int orow[4]; float cjv[4];
    #pragma unroll
    for (int i = 0; i < 4; ++i) {
        orow[i] = rowbase + kq * 4 + i;
        cjv[i] = cj[orow[i] < N_NODES ? orow[i] : 0];
    }
    #pragma unroll
    for (int f = 0; f < 8; ++f) {
        int c = f * 16 + r;
        #pragma unroll
        for (int i = 0; i < 4; ++i) {
            if (orow[i] < N_NODES)
                h[(size_t)orow[i] * OUT_F + c] = (unsigned short)f2bf(acc[f][i] * cjv[i]);
        }
    }
}

// ---------------- Node-degree exclusive scan (3 phases) ----------------
__global__ __launch_bounds__(256) void scan_phaseA(const int* __restrict__ counts,
                                                   int* __restrict__ block_sums) {
    __shared__ int sdata[256];
    int t = threadIdx.x;
    int gi4 = blockIdx.x * 256 + t;
    int v = 0;
    if (gi4 < N4) {
        int4 x = reinterpret_cast<const int4*>(counts)[gi4];
        v = (x.x + x.y) + (x.z + x.w);
    }
    sdata[t] = v;
    __syncthreads();
    #pragma unroll
    for (int s = 128; s > 0; s >>= 1) {
        if (t < s) sdata[t] += sdata[t + s];
        __syncthreads();
    }
    if (t == 0) block_sums[blockIdx.x] = sdata[0];
}

__global__ __launch_bounds__(128) void scan_phaseB(int* __restrict__ block_sums) {
    __shared__ int sdata[128];
    int t = threadIdx.x;
    int v = (t < SCAN_NB) ? block_sums[t] : 0;
    sdata[t] = v;
    __syncthreads();
    #pragma unroll
    for (int off = 1; off < 128; off <<= 1) {
        int u = (t >= off) ? sdata[t - off] : 0;
        __syncthreads();
        sdata[t] += u;
        __syncthreads();
    }
    if (t < SCAN_NB) block_sums[t] = sdata[t] - v;
}

__global__ __launch_bounds__(256) void scan_phaseC(const int* __restrict__ block_sums,
                                                   const int* __restrict__ counts,
                                                   int* __restrict__ offsets) {
    __shared__ int sdata[256];
    int t = threadIdx.x;
    int gi4 = blockIdx.x * 256 + t;
    int4 x = make_int4(0, 0, 0, 0);
    bool valid = gi4 < N4;
    if (valid) x = reinterpret_cast<const int4*>(counts)[gi4];
    int tot = (x.x + x.y) + (x.z + x.w);
    sdata[t] = tot;
    __syncthreads();
    #pragma unroll
    for (int off = 1; off < 256; off <<= 1) {
        int u = (t >= off) ? sdata[t - off] : 0;
        __syncthreads();
        sdata[t] += u;
        __syncthreads();
    }
    if (valid) {
        int base = block_sums[blockIdx.x] + sdata[t] - tot;
        int4 o;
        o.x = base;
        o.y = base + x.x;
        o.z = o.y + x.y;
        o.w = o.z + x.z;
        reinterpret_cast<int4*>(offsets)[gi4] = o;
    }
    if (blockIdx.x == 0 && t == 0) offsets[N_NODES] = N_EDGES;
}

// bucket_base[b] = offsets[min(b*NPB, N)]; cursor init = base. 257 entries.
__global__ __launch_bounds__(512) void bucket_base_kernel(const int* __restrict__ offsets,
                                                          int* __restrict__ bucket_base,
                                                          int* __restrict__ bucket_cursor) {
    int t = threadIdx.x;
    if (t <= BUCKETS) {
        int nidx = t * NPB;
        if (nidx > N_NODES) nidx = N_NODES;
        int v = offsets[nidx];
        bucket_base[t] = v;
        if (t < BUCKETS) bucket_cursor[t] = v;
    }
}

// ---------------- P1: LDS-staged partition of (dst,src) into 256 buckets -----
// Per 4096-edge chunk: LDS histogram+rank -> LDS scan -> LDS reorder ->
// one global atomicAdd per bucket -> sequential burst copy to pair_buf.
__global__ __launch_bounds__(256) void partition_kernel(const int* __restrict__ src,
                                                        const int* __restrict__ dst,
                                                        int* __restrict__ bucket_cursor,
                                                        uint2* __restrict__ pair_buf) {
    __shared__ int hist[BUCKETS];
    __shared__ int hstart[BUCKETS];
    __shared__ int gbase[BUCKETS];
    __shared__ uint2 stage[CH];       // 32 KB

    const int t = threadIdx.x;
    const int e0 = blockIdx.x * CH;
    int nE = N_EDGES - e0;
    if (nE > CH) nE = CH;

    hist[t] = 0;
    __syncthreads();

    int d_[16], rank_[16];
    const int4* d4 = reinterpret_cast<const int4*>(dst);
    #pragma unroll
    for (int i = 0; i < 4; ++i) {
        int li = t + i * 256;                 // local int4 idx (0..1023)
        int g4 = (e0 >> 2) + li;
        if (li * 4 < nE && g4 < E4) {
            int4 d = d4[g4];
            d_[i*4+0] = d.x; d_[i*4+1] = d.y; d_[i*4+2] = d.z; d_[i*4+3] = d.w;
            rank_[i*4+0] = atomicAdd(&hist[d.x / NPB], 1);
            rank_[i*4+1] = atomicAdd(&hist[d.y / NPB], 1);
            rank_[i*4+2] = atomicAdd(&hist[d.z / NPB], 1);
            rank_[i*4+3] = atomicAdd(&hist[d.w / NPB], 1);
        } else {
            d_[i*4+0] = -1; d_[i*4+1] = -1; d_[i*4+2] = -1; d_[i*4+3] = -1;
        }
    }
    __syncthreads();

    int v = hist[t];
    hstart[t] = v;
    __syncthreads();
    #pragma unroll
    for (int off = 1; off < 256; off <<= 1) {
        int u = (t >= off) ? hstart[t - off] : 0;
        __syncthreads();
        hstart[t] += u;
        __syncthreads();
    }
    int startl = hstart[t] - v;               // exclusive local start
    if (v > 0) gbase[t] = atomicAdd(&bucket_cursor[t], v);
    __syncthreads();
    hstart[t] = startl;
    __syncthreads();

    // scatter pairs into LDS, bucket-sorted
    const int4* s4 = reinterpret_cast<const int4*>(src);
    #pragma unroll
    for (int i = 0; i < 4; ++i) {
        int li = t + i * 256;
        int g4 = (e0 >> 2) + li;
        if (d_[i*4] >= 0) {
            int4 s = s4[g4];
            stage[hstart[d_[i*4+0] / NPB] + rank_[i*4+0]] = make_uint2((unsigned)d_[i*4+0], (unsigned)s.x);
            stage[hstart[d_[i*4+1] / NPB] + rank_[i*4+1]] = make_uint2((unsigned)d_[i*4+1], (unsigned)s.y);
            stage[hstart[d_[i*4+2] / NPB] + rank_[i*4+2]] = make_uint2((unsigned)d_[i*4+2], (unsigned)s.z);
            stage[hstart[d_[i*4+3] / NPB] + rank_[i*4+3]] = make_uint2((unsigned)d_[i*4+3], (unsigned)s.w);
        }
    }
    __syncthreads();

    // burst copy: consecutive idx -> consecutive global addresses per bucket run
    for (int idx = t; idx < nE; idx += 256) {
        uint2 p = stage[idx];
        int b = (int)p.x / NPB;
        pair_buf[gbase[b] + (idx - hstart[b])] = p;
    }
}

// ---------------- P2: bin within bucket (one block per bucket) ----------------
__global__ __launch_bounds__(256) void bin_kernel(const uint2* __restrict__ pair_buf,
                                                  const int* __restrict__ offsets,
                                                  const int* __restrict__ bucket_base,
                                                  int* __restrict__ bin_src) {
    __shared__ int cur[NPB];
    const int b = blockIdx.x;
    const int t = threadIdx.x;
    const int nlo = b * NPB;
    int nn = N_NODES - nlo;
    if (nn > NPB) nn = NPB;
    for (int j = t; j < nn; j += 256) cur[j] = offsets[nlo + j];
    __syncthreads();

    const int beg = bucket_base[b];
    const int end = bucket_base[b + 1];
    for (int i = beg + t; i < end; i += 256) {
        uint2 p = pair_buf[i];
        int pos = atomicAdd(&cur[(int)p.x - nlo], 1);
        bin_src[pos] = (int)p.y;
    }
}

// ---------------- Gather: out[d][c] = ci[d] * sum_{e in bin(d)} h_bf16[src_e][c] --
__global__ __launch_bounds__(256) void gather_kernel(const unsigned int* __restrict__ h,
                                                     const float* __restrict__ ci,
                                                     const int* __restrict__ offsets,
                                                     const int* __restrict__ bin_src,
                                                     float* __restrict__ out) {
    int node = blockIdx.x * 8 + (threadIdx.x >> 5);
    int lane = threadIdx.x & 31;
    if (node >= N_NODES) return;

    int beg = offsets[node];
    int end = offsets[node + 1];
    const uint2* h2 = reinterpret_cast<const uint2*>(h);

    float4 acc = make_float4(0, 0, 0, 0);
    int i = beg;
    for (; i + 4 <= end; i += 4) {
        int s0 = bin_src[i + 0];
        int s1 = bin_src[i + 1];
        int s2 = bin_src[i + 2];
        int s3 = bin_src[i + 3];
        uint2 v0 = h2[(size_t)s0 * 32 + lane];
        uint2 v1 = h2[(size_t)s1 * 32 + lane];
        uint2 v2 = h2[(size_t)s2 * 32 + lane];
        uint2 v3 = h2[(size_t)s3 * 32 + lane];
        acc.x += (bf_lo(v0.x) + bf_lo(v1.x)) + (bf_lo(v2.x) + bf_lo(v3.x));
        acc.y += (bf_hi(v0.x) + bf_hi(v1.x)) + (bf_hi(v2.x) + bf_hi(v3.x));
        acc.z += (bf_lo(v0.y) + bf_lo(v1.y)) + (bf_lo(v2.y) + bf_lo(v3.y));
        acc.w += (bf_hi(v0.y) + bf_hi(v1.y)) + (bf_hi(v2.y) + bf_hi(v3.y));
    }
    for (; i < end; ++i) {
        int s = bin_src[i];
        uint2 v = h2[(size_t)s * 32 + lane];
        acc.x += bf_lo(v.x);
        acc.y += bf_hi(v.x);
        acc.z += bf_lo(v.y);
        acc.w += bf_hi(v.y);
    }
    float sc = ci[node];
    acc.x *= sc; acc.y *= sc; acc.z *= sc; acc.w *= sc;
    reinterpret_cast<float4*>(out)[(size_t)node * 32 + lane] = acc;
}

extern "C" void kernel_launch(void* const* d_in, const int* in_sizes, int n_in,
                              void* d_out, int out_size, void* d_ws, size_t ws_size,
                              hipStream_t stream) {
    const float* feat = (const float*)d_in[0];
    const float* W    = (const float*)d_in[1];
    const float* cj   = (const float*)d_in[2];
    const float* ci   = (const float*)d_in[3];
    const int*   src  = (const int*)d_in[4];
    const int*   dst  = (const int*)d_in[5];
    float* out = (float*)d_out;

    const size_t H_BYTES   = (size_t)N_NODES * OUT_F * 2;          // 25.6 MB
    const size_t WT_BYTES  = (size_t)IN_F * OUT_F * 2;             // 64 KB
    const size_t OFF_BYTES = (((size_t)(N_NODES + 1) * 4) + 15) & ~(size_t)15;
    const size_t CNT_BYTES = (size_t)N_NODES * 4;                  // 400 KB
    const size_t BS_BYTES  = (((size_t)SCAN_NB * 4) + 15) & ~(size_t)15;
    const size_t BB_BYTES  = (((size_t)(BUCKETS + 1) * 4) + 15) & ~(size_t)15;
    const size_t BC_BYTES  = (size_t)BUCKETS * 4;                  // 1 KB
    const size_t PAIR_BYTES = (size_t)N_EDGES * 8;                 // 12.8 MB

    char* ws = (char*)d_ws;
    unsigned short* h  = (unsigned short*)ws;  ws += H_BYTES;
    unsigned short* Wt = (unsigned short*)ws;  ws += WT_BYTES;
    int* offsets       = (int*)ws;             ws += OFF_BYTES;
    int* counts        = (int*)ws;             ws += CNT_BYTES;
    int* block_sums    = (int*)ws;             ws += BS_BYTES;
    int* bucket_base   = (int*)ws;             ws += BB_BYTES;
    int* bucket_cursor = (int*)ws;             ws += BC_BYTES;
    uint2* pair_buf    = (uint2*)ws;           ws += PAIR_BYTES;
    int* bin_src       = (int*)ws;

    wprep_kernel<<<128, 256, 0, stream>>>(W, Wt);
    hipMemsetAsync(counts, 0, CNT_BYTES, stream);

    gemm_count_kernel<<<GC_BLOCKS, 256, 0, stream>>>(feat, Wt, cj, h, dst, counts);

    scan_phaseA<<<SCAN_NB, 256, 0, stream>>>(counts, block_sums);
    scan_phaseB<<<1, 128, 0, stream>>>(block_sums);
    scan_phaseC<<<SCAN_NB, 256, 0, stream>>>(block_sums, counts, offsets);
    bucket_base_kernel<<<1, 512, 0, stream>>>(offsets, bucket_base, bucket_cursor);

    partition_kernel<<<NCHUNK, 256, 0, stream>>>(src, dst, bucket_cursor, pair_buf);
    bin_kernel<<<BUCKETS, 256, 0, stream>>>(pair_buf, offsets, bucket_base, bin_src);

    gather_kernel<<<(N_NODES + 7) / 8, 256, 0, stream>>>((const unsigned int*)h, ci, offsets, bin_src, out);
}

// Round 9
// 199.478 us; speedup vs baseline: 2.0769x; 1.1359x over previous
//
#include <hip/hip_runtime.h>

#define N_NODES 100000
#define N_EDGES 1600000
#define IN_F 256
#define OUT_F 128

#define N4 (N_NODES / 4)               // 25000
#define SCAN_NB ((N4 + 255) / 256)     // 98
#define E4 (N_EDGES / 4)               // 400000

#define BUCKETS 256
#define NPB 391                        // 256*391 >= N_NODES
#define CH 4096
#define NCHUNK ((N_EDGES + CH - 1) / CH)   // 391

#define GEMM_BLOCKS ((N_NODES + 127) / 128)  // 782 (128 rows/block, 8 waves)
#define CNT_BLOCKS 196
#define GC_BLOCKS (GEMM_BLOCKS + CNT_BLOCKS)

typedef short bf16x8 __attribute__((ext_vector_type(8)));
typedef float f32x4 __attribute__((ext_vector_type(4)));

// ---- bf16 helpers (RNE) ----
__device__ __forceinline__ unsigned int f2bf(float f) {
    unsigned int u = __float_as_uint(f);
    return (u + 0x7FFFu + ((u >> 16) & 1u)) >> 16;
}
__device__ __forceinline__ unsigned int pack2(float a, float b) {
    return f2bf(a) | (f2bf(b) << 16);
}
__device__ __forceinline__ float bf_lo(unsigned int u) { return __uint_as_float(u << 16); }
__device__ __forceinline__ float bf_hi(unsigned int u) { return __uint_as_float(u & 0xFFFF0000u); }

// ---------------- W prep: fragment-ordered bf16 Wfrag -------------------------
// Wfrag[((f*8+kt)*64 + lane)*8 + j] = bf16( W[(kt*32 + (lane>>4)*8 + j)][f*16 + (lane&15)] )
// so a wave's b-frag for (f,kt) is 64 lanes x 16B contiguous.
__global__ __launch_bounds__(256) void wprep_kernel(const float* __restrict__ W,
                                                    unsigned short* __restrict__ Wfrag) {
    int idx = blockIdx.x * 256 + threadIdx.x;       // 32768 total
    if (idx < IN_F * OUT_F) {
        int j    = idx & 7;
        int lane = (idx >> 3) & 63;
        int fkt  = idx >> 9;
        int f    = fkt >> 3;
        int kt   = fkt & 7;
        int c    = f * 16 + (lane & 15);
        int k    = kt * 32 + (lane >> 4) * 8 + j;
        Wfrag[idx] = (unsigned short)f2bf(W[k * OUT_F + c]);
    }
}

// ---------------- Fused: MFMA gemm (h = bf16((feat@W)*cj)) + degree count -----
// gemm role: 512 thr = 8 waves, 128 rows/block. Wfrag staged to LDS once
// (coalesced), b-frags via conflict-free ds_read_b128; feat loads issued as an
// upfront 16-deep independent burst.
__global__ __launch_bounds__(512) void gemm_count_kernel(const float* __restrict__ feat,
                                                         const unsigned short* __restrict__ Wfrag,
                                                         const float* __restrict__ cj,
                                                         unsigned short* __restrict__ h,
                                                         const int* __restrict__ dst,
                                                         int* __restrict__ counts) {
    __shared__ unsigned short wl[64 * 64 * 8];   // 64 KB, fragment-ordered

    const int bid = blockIdx.x;
    const int tid = threadIdx.x;

    if (bid >= GEMM_BLOCKS) {
        // ---- count role (grid-stride, 4 atomics per int4) ----
        int cb = bid - GEMM_BLOCKS;
        const int4* d4 = reinterpret_cast<const int4*>(dst);
        for (int g4 = cb * 512 + tid; g4 < E4; g4 += CNT_BLOCKS * 512) {
            int4 d = d4[g4];
            atomicAdd(&counts[d.x], 1);
            atomicAdd(&counts[d.y], 1);
            atomicAdd(&counts[d.z], 1);
            atomicAdd(&counts[d.w], 1);
        }
        return;
    }

    // ---- gemm role ----
    const int wave = tid >> 6;
    const int lane = tid & 63;
    const int r  = lane & 15;
    const int kq = lane >> 4;
    const int rowbase = bid * 128 + wave * 16;

    int arow = rowbase + r;
    if (arow >= N_NODES) arow = N_NODES - 1;
    const float4* fr4 = reinterpret_cast<const float4*>(feat + (size_t)arow * IN_F);

    // upfront feat burst: 16 independent dwordx4
    float4 fv[16];
    #pragma unroll
    for (int kt = 0; kt < 8; ++kt) {
        fv[2 * kt]     = fr4[kt * 8 + kq * 2];
        fv[2 * kt + 1] = fr4[kt * 8 + kq * 2 + 1];
    }

    // stage Wfrag -> LDS, coalesced (latency overlaps feat burst)
    {
        const uint4* wsrc = reinterpret_cast<const uint4*>(Wfrag);
        uint4* wdst = reinterpret_cast<uint4*>(wl);
        #pragma unroll
        for (int i = 0; i < 8; ++i) wdst[tid + i * 512] = wsrc[tid + i * 512];
    }

    // convert feat to bf16 a-frags
    bf16x8 a[8];
    #pragma unroll
    for (int kt = 0; kt < 8; ++kt) {
        uint4 au;
        au.x = pack2(fv[2 * kt].x,     fv[2 * kt].y);
        au.y = pack2(fv[2 * kt].z,     fv[2 * kt].w);
        au.z = pack2(fv[2 * kt + 1].x, fv[2 * kt + 1].y);
        au.w = pack2(fv[2 * kt + 1].z, fv[2 * kt + 1].w);
        a[kt] = *reinterpret_cast<bf16x8*>(&au);
    }
    __syncthreads();

    f32x4 acc[8];
    #pragma unroll
    for (int f = 0; f < 8; ++f) acc[f] = (f32x4){0.f, 0.f, 0.f, 0.f};

    // kt outer, f inner: 8 independent acc chains per kt
    #pragma unroll
    for (int kt = 0; kt < 8; ++kt) {
        #pragma unroll
        for (int f = 0; f < 8; ++f) {
            bf16x8 b = *reinterpret_cast<const bf16x8*>(&wl[((f * 8 + kt) * 64 + lane) * 8]);
            acc[f] = __builtin_amdgcn_mfma_f32_16x16x32_bf16(a[kt], b, acc[f], 0, 0, 0);
        }
    }

    // epilogue: C/D layout col = lane&15, row = (lane>>4)*4 + reg  (verified r8)
    int orow[4]; float cjv[4];
    #pragma unroll
    for (int i = 0; i < 4; ++i) {
        orow[i] = rowbase + kq * 4 + i;
        cjv[i] = cj[orow[i] < N_NODES ? orow[i] : 0];
    }
    #pragma unroll
    for (int f = 0; f < 8; ++f) {
        int c = f * 16 + r;
        #pragma unroll
        for (int i = 0; i < 4; ++i) {
            if (orow[i] < N_NODES)
                h[(size_t)orow[i] * OUT_F + c] = (unsigned short)f2bf(acc[f][i] * cjv[i]);
        }
    }
}

// ---------------- Node-degree exclusive scan (3 phases) ----------------
__global__ __launch_bounds__(256) void scan_phaseA(const int* __restrict__ counts,
                                                   int* __restrict__ block_sums) {
    __shared__ int sdata[256];
    int t = threadIdx.x;
    int gi4 = blockIdx.x * 256 + t;
    int v = 0;
    if (gi4 < N4) {
        int4 x = reinterpret_cast<const int4*>(counts)[gi4];
        v = (x.x + x.y) + (x.z + x.w);
    }
    sdata[t] = v;
    __syncthreads();
    #pragma unroll
    for (int s = 128; s > 0; s >>= 1) {
        if (t < s) sdata[t] += sdata[t + s];
        __syncthreads();
    }
    if (t == 0) block_sums[blockIdx.x] = sdata[0];
}

__global__ __launch_bounds__(128) void scan_phaseB(int* __restrict__ block_sums) {
    __shared__ int sdata[128];
    int t = threadIdx.x;
    int v = (t < SCAN_NB) ? block_sums[t] : 0;
    sdata[t] = v;
    __syncthreads();
    #pragma unroll
    for (int off = 1; off < 128; off <<= 1) {
        int u = (t >= off) ? sdata[t - off] : 0;
        __syncthreads();
        sdata[t] += u;
        __syncthreads();
    }
    if (t < SCAN_NB) block_sums[t] = sdata[t] - v;
}

__global__ __launch_bounds__(256) void scan_phaseC(const int* __restrict__ block_sums,
                                                   const int* __restrict__ counts,
                                                   int* __restrict__ offsets) {
    __shared__ int sdata[256];
    int t = threadIdx.x;
    int gi4 = blockIdx.x * 256 + t;
    int4 x = make_int4(0, 0, 0, 0);
    bool valid = gi4 < N4;
    if (valid) x = reinterpret_cast<const int4*>(counts)[gi4];
    int tot = (x.x + x.y) + (x.z + x.w);
    sdata[t] = tot;
    __syncthreads();
    #pragma unroll
    for (int off = 1; off < 256; off <<= 1) {
        int u = (t >= off) ? sdata[t - off] : 0;
        __syncthreads();
        sdata[t] += u;
        __syncthreads();
    }
    if (valid) {
        int base = block_sums[blockIdx.x] + sdata[t] - tot;
        int4 o;
        o.x = base;
        o.y = base + x.x;
        o.z = o.y + x.y;
        o.w = o.z + x.z;
        reinterpret_cast<int4*>(offsets)[gi4] = o;
    }
    if (blockIdx.x == 0 && t == 0) offsets[N_NODES] = N_EDGES;
}

__global__ __launch_bounds__(512) void bucket_base_kernel(const int* __restrict__ offsets,
                                                          int* __restrict__ bucket_base,
                                                          int* __restrict__ bucket_cursor) {
    int t = threadIdx.x;
    if (t <= BUCKETS) {
        int nidx = t * NPB;
        if (nidx > N_NODES) nidx = N_NODES;
        int v = offsets[nidx];
        bucket_base[t] = v;
        if (t < BUCKETS) bucket_cursor[t] = v;
    }
}

// ---------------- P1: LDS-staged partition into 256 buckets ----------------
__global__ __launch_bounds__(256) void partition_kernel(const int* __restrict__ src,
                                                        const int* __restrict__ dst,
                                                        int* __restrict__ bucket_cursor,
                                                        uint2* __restrict__ pair_buf) {
    __shared__ int hist[BUCKETS];
    __shared__ int hstart[BUCKETS];
    __shared__ int gbase[BUCKETS];
    __shared__ uint2 stage[CH];       // 32 KB

    const int t = threadIdx.x;
    const int e0 = blockIdx.x * CH;
    int nE = N_EDGES - e0;
    if (nE > CH) nE = CH;

    hist[t] = 0;
    __syncthreads();

    int d_[16], rank_[16];
    const int4* d4 = reinterpret_cast<const int4*>(dst);
    #pragma unroll
    for (int i = 0; i < 4; ++i) {
        int li = t + i * 256;
        int g4 = (e0 >> 2) + li;
        if (li * 4 < nE && g4 < E4) {
            int4 d = d4[g4];
            d_[i*4+0] = d.x; d_[i*4+1] = d.y; d_[i*4+2] = d.z; d_[i*4+3] = d.w;
            rank_[i*4+0] = atomicAdd(&hist[d.x / NPB], 1);
            rank_[i*4+1] = atomicAdd(&hist[d.y / NPB], 1);
            rank_[i*4+2] = atomicAdd(&hist[d.z / NPB], 1);
            rank_[i*4+3] = atomicAdd(&hist[d.w / NPB], 1);
        } else {
            d_[i*4+0] = -1; d_[i*4+1] = -1; d_[i*4+2] = -1; d_[i*4+3] = -1;
        }
    }
    __syncthreads();

    int v = hist[t];
    hstart[t] = v;
    __syncthreads();
    #pragma unroll
    for (int off = 1; off < 256; off <<= 1) {
        int u = (t >= off) ? hstart[t - off] : 0;
        __syncthreads();
        hstart[t] += u;
        __syncthreads();
    }
    int startl = hstart[t] - v;
    if (v > 0) gbase[t] = atomicAdd(&bucket_cursor[t], v);
    __syncthreads();
    hstart[t] = startl;
    __syncthreads();

    const int4* s4 = reinterpret_cast<const int4*>(src);
    #pragma unroll
    for (int i = 0; i < 4; ++i) {
        int li = t + i * 256;
        int g4 = (e0 >> 2) + li;
        if (d_[i*4] >= 0) {
            int4 s = s4[g4];
            stage[hstart[d_[i*4+0] / NPB] + rank_[i*4+0]] = make_uint2((unsigned)d_[i*4+0], (unsigned)s.x);
            stage[hstart[d_[i*4+1] / NPB] + rank_[i*4+1]] = make_uint2((unsigned)d_[i*4+1], (unsigned)s.y);
            stage[hstart[d_[i*4+2] / NPB] + rank_[i*4+2]] = make_uint2((unsigned)d_[i*4+2], (unsigned)s.z);
            stage[hstart[d_[i*4+3] / NPB] + rank_[i*4+3]] = make_uint2((unsigned)d_[i*4+3], (unsigned)s.w);
        }
    }
    __syncthreads();

    for (int idx = t; idx < nE; idx += 256) {
        uint2 p = stage[idx];
        int b = (int)p.x / NPB;
        pair_buf[gbase[b] + (idx - hstart[b])] = p;
    }
}

// ---------------- P2: bin within bucket ----------------
__global__ __launch_bounds__(256) void bin_kernel(const uint2* __restrict__ pair_buf,
                                                  const int* __restrict__ offsets,
                                                  const int* __restrict__ bucket_base,
                                                  int* __restrict__ bin_src) {
    __shared__ int cur[NPB];
    const int b = blockIdx.x;
    const int t = threadIdx.x;
    const int nlo = b * NPB;
    int nn = N_NODES - nlo;
    if (nn > NPB) nn = NPB;
    for (int j = t; j < nn; j += 256) cur[j] = offsets[nlo + j];
    __syncthreads();

    const int beg = bucket_base[b];
    const int end = bucket_base[b + 1];
    for (int i = beg + t; i < end; i += 256) {
        uint2 p = pair_buf[i];
        int pos = atomicAdd(&cur[(int)p.x - nlo], 1);
        bin_src[pos] = (int)p.y;
    }
}

// ---------------- Gather ----------------
__global__ __launch_bounds__(256) void gather_kernel(const unsigned int* __restrict__ h,
                                                     const float* __restrict__ ci,
                                                     const int* __restrict__ offsets,
                                                     const int* __restrict__ bin_src,
                                                     float* __restrict__ out) {
    int node = blockIdx.x * 8 + (threadIdx.x >> 5);
    int lane = threadIdx.x & 31;
    if (node >= N_NODES) return;

    int beg = offsets[node];
    int end = offsets[node + 1];
    const uint2* h2 = reinterpret_cast<const uint2*>(h);

    float4 acc = make_float4(0, 0, 0, 0);
    int i = beg;
    for (; i + 4 <= end; i += 4) {
        int s0 = bin_src[i + 0];
        int s1 = bin_src[i + 1];
        int s2 = bin_src[i + 2];
        int s3 = bin_src[i + 3];
        uint2 v0 = h2[(size_t)s0 * 32 + lane];
        uint2 v1 = h2[(size_t)s1 * 32 + lane];
        uint2 v2 = h2[(size_t)s2 * 32 + lane];
        uint2 v3 = h2[(size_t)s3 * 32 + lane];
        acc.x += (bf_lo(v0.x) + bf_lo(v1.x)) + (bf_lo(v2.x) + bf_lo(v3.x));
        acc.y += (bf_hi(v0.x) + bf_hi(v1.x)) + (bf_hi(v2.x) + bf_hi(v3.x));
        acc.z += (bf_lo(v0.y) + bf_lo(v1.y)) + (bf_lo(v2.y) + bf_lo(v3.y));
        acc.w += (bf_hi(v0.y) + bf_hi(v1.y)) + (bf_hi(v2.y) + bf_hi(v3.y));
    }
    for (; i < end; ++i) {
        int s = bin_src[i];
        uint2 v = h2[(size_t)s * 32 + lane];
        acc.x += bf_lo(v.x);
        acc.y += bf_hi(v.x);
        acc.z += bf_lo(v.y);
        acc.w += bf_hi(v.y);
    }
    float sc = ci[node];
    acc.x *= sc; acc.y *= sc; acc.z *= sc; acc.w *= sc;
    reinterpret_cast<float4*>(out)[(size_t)node * 32 + lane] = acc;
}

extern "C" void kernel_launch(void* const* d_in, const int* in_sizes, int n_in,
                              void* d_out, int out_size, void* d_ws, size_t ws_size,
                              hipStream_t stream) {
    const float* feat = (const float*)d_in[0];
    const float* W    = (const float*)d_in[1];
    const float* cj   = (const float*)d_in[2];
    const float* ci   = (const float*)d_in[3];
    const int*   src  = (const int*)d_in[4];
    const int*   dst  = (const int*)d_in[5];
    float* out = (float*)d_out;

    const size_t H_BYTES   = (size_t)N_NODES * OUT_F * 2;          // 25.6 MB
    const size_t WT_BYTES  = (size_t)IN_F * OUT_F * 2;             // 64 KB
    const size_t OFF_BYTES = (((size_t)(N_NODES + 1) * 4) + 15) & ~(size_t)15;
    const size_t CNT_BYTES = (size_t)N_NODES * 4;
    const size_t BS_BYTES  = (((size_t)SCAN_NB * 4) + 15) & ~(size_t)15;
    const size_t BB_BYTES  = (((size_t)(BUCKETS + 1) * 4) + 15) & ~(size_t)15;
    const size_t BC_BYTES  = (size_t)BUCKETS * 4;
    const size_t PAIR_BYTES = (size_t)N_EDGES * 8;                 // 12.8 MB

    char* ws = (char*)d_ws;
    unsigned short* h     = (unsigned short*)ws;  ws += H_BYTES;
    unsigned short* Wfrag = (unsigned short*)ws;  ws += WT_BYTES;
    int* offsets       = (int*)ws;             ws += OFF_BYTES;
    int* counts        = (int*)ws;             ws += CNT_BYTES;
    int* block_sums    = (int*)ws;             ws += BS_BYTES;
    int* bucket_base   = (int*)ws;             ws += BB_BYTES;
    int* bucket_cursor = (int*)ws;             ws += BC_BYTES;
    uint2* pair_buf    = (uint2*)ws;           ws += PAIR_BYTES;
    int* bin_src       = (int*)ws;

    wprep_kernel<<<128, 256, 0, stream>>>(W, Wfrag);
    hipMemsetAsync(counts, 0, CNT_BYTES, stream);

    gemm_count_kernel<<<GC_BLOCKS, 512, 0, stream>>>(feat, Wfrag, cj, h, dst, counts);

    scan_phaseA<<<SCAN_NB, 256, 0, stream>>>(counts, block_sums);
    scan_phaseB<<<1, 128, 0, stream>>>(block_sums);
    scan_phaseC<<<SCAN_NB, 256, 0, stream>>>(block_sums, counts, offsets);
    bucket_base_kernel<<<1, 512, 0, stream>>>(offsets, bucket_base, bucket_cursor);

    partition_kernel<<<NCHUNK, 256, 0, stream>>>(src, dst, bucket_cursor, pair_buf);
    bin_kernel<<<BUCKETS, 256, 0, stream>>>(pair_buf, offsets, bucket_base, bin_src);

    gather_kernel<<<(N_NODES + 7) / 8, 256, 0, stream>>>((const unsigned int*)h, ci, offsets, bin_src, out);
}

// Round 10
// 127.646 us; speedup vs baseline: 3.2456x; 1.5627x over previous
//
#include <hip/hip_runtime.h>

#define N_NODES 100000
#define N_EDGES 1600000
#define IN_F 256
#define OUT_F 128
#define E4 (N_EDGES / 4)

#define BUCKETS 256
#define NPB 391                        // 256*391 = 100096 >= N_NODES
#define CH 4096
#define NCHUNK ((N_EDGES + CH - 1) / CH)   // 391
#define CAP 8192                       // slab capacity/bucket: mean 6250, sd ~79 -> +24 sd

#define GEMM_BLOCKS ((N_NODES + 127) / 128)  // 782 (128 rows/block, 8 waves)
#define GP_BLOCKS (GEMM_BLOCKS + NCHUNK)     // 1173

typedef short bf16x8 __attribute__((ext_vector_type(8)));
typedef float f32x4 __attribute__((ext_vector_type(4)));

// ---- bf16 helpers (RNE) ----
__device__ __forceinline__ unsigned int f2bf(float f) {
    unsigned int u = __float_as_uint(f);
    return (u + 0x7FFFu + ((u >> 16) & 1u)) >> 16;
}
__device__ __forceinline__ unsigned int pack2(float a, float b) {
    return f2bf(a) | (f2bf(b) << 16);
}
__device__ __forceinline__ float bf_lo(unsigned int u) { return __uint_as_float(u << 16); }
__device__ __forceinline__ float bf_hi(unsigned int u) { return __uint_as_float(u & 0xFFFF0000u); }

// ---------------- W prep: fragment-ordered bf16 Wfrag (as r9, verified) -------
__global__ __launch_bounds__(256) void wprep_kernel(const float* __restrict__ W,
                                                    unsigned short* __restrict__ Wfrag) {
    int idx = blockIdx.x * 256 + threadIdx.x;
    if (idx < IN_F * OUT_F) {
        int j    = idx & 7;
        int lane = (idx >> 3) & 63;
        int fkt  = idx >> 9;
        int f    = fkt >> 3;
        int kt   = fkt & 7;
        int c    = f * 16 + (lane & 15);
        int k    = kt * 32 + (lane >> 4) * 8 + j;
        Wfrag[idx] = (unsigned short)f2bf(W[k * OUT_F + c]);
    }
}

// ---------------- Fused: MFMA gemm + LDS-staged bucket partition --------------
// gemm role (bid < GEMM_BLOCKS): as r9, but epilogue stages the 16x128 bf16
//   tile per wave in padded LDS and stores h as full 64B lines (uint4).
// partition role: per 4096-edge chunk, LDS histogram over 256 buckets ->
//   LDS scan -> LDS reorder -> 1 atomic per (block,bucket) on bucket_cursor
//   (256 ints only) -> burst copy into per-bucket slab. No global node atomics.
__global__ __launch_bounds__(512) void gemm_part_kernel(const float* __restrict__ feat,
                                                        const unsigned short* __restrict__ Wfrag,
                                                        const float* __restrict__ cj,
                                                        unsigned short* __restrict__ h,
                                                        const int* __restrict__ src,
                                                        const int* __restrict__ dst,
                                                        int* __restrict__ bucket_cursor,
                                                        uint2* __restrict__ slab) {
    __shared__ __align__(16) char pool[65536];

    const int bid = blockIdx.x;
    const int tid = threadIdx.x;

    if (bid >= GEMM_BLOCKS) {
        // ---- partition role ----
        int* hist   = (int*)pool;             // 256
        int* hstart = hist + 256;             // 256
        int* gbase  = hstart + 256;           // 256
        uint2* stage = (uint2*)(pool + 3072); // 4096 uint2 = 32 KB

        const int cb = bid - GEMM_BLOCKS;
        const int e0 = cb * CH;
        int nE = N_EDGES - e0;
        if (nE > CH) nE = CH;

        if (tid < 256) hist[tid] = 0;
        __syncthreads();

        int dv[8], rk[8];
        const int4* d4 = reinterpret_cast<const int4*>(dst);
        #pragma unroll
        for (int i = 0; i < 2; ++i) {
            int li = tid + i * 512;
            int g4 = (e0 >> 2) + li;
            if (li * 4 < nE && g4 < E4) {
                int4 d = d4[g4];
                dv[i*4+0] = d.x; dv[i*4+1] = d.y; dv[i*4+2] = d.z; dv[i*4+3] = d.w;
                rk[i*4+0] = atomicAdd(&hist[d.x / NPB], 1);
                rk[i*4+1] = atomicAdd(&hist[d.y / NPB], 1);
                rk[i*4+2] = atomicAdd(&hist[d.z / NPB], 1);
                rk[i*4+3] = atomicAdd(&hist[d.w / NPB], 1);
            } else {
                dv[i*4+0] = -1; dv[i*4+1] = -1; dv[i*4+2] = -1; dv[i*4+3] = -1;
            }
        }
        __syncthreads();

        int v = 0;
        if (tid < 256) { v = hist[tid]; hstart[tid] = v; }
        __syncthreads();
        #pragma unroll
        for (int off = 1; off < 256; off <<= 1) {
            int u = 0;
            if (tid < 256 && tid >= off) u = hstart[tid - off];
            __syncthreads();
            if (tid < 256) hstart[tid] += u;
            __syncthreads();
        }
        if (tid < 256) {
            int ex = hstart[tid] - v;
            if (v > 0) gbase[tid] = atomicAdd(&bucket_cursor[tid], v);
            hstart[tid] = ex;
        }
        __syncthreads();

        const int4* s4 = reinterpret_cast<const int4*>(src);
        #pragma unroll
        for (int i = 0; i < 2; ++i) {
            int li = tid + i * 512;
            int g4 = (e0 >> 2) + li;
            if (dv[i*4] >= 0) {
                int4 s = s4[g4];
                stage[hstart[dv[i*4+0] / NPB] + rk[i*4+0]] = make_uint2((unsigned)dv[i*4+0], (unsigned)s.x);
                stage[hstart[dv[i*4+1] / NPB] + rk[i*4+1]] = make_uint2((unsigned)dv[i*4+1], (unsigned)s.y);
                stage[hstart[dv[i*4+2] / NPB] + rk[i*4+2]] = make_uint2((unsigned)dv[i*4+2], (unsigned)s.z);
                stage[hstart[dv[i*4+3] / NPB] + rk[i*4+3]] = make_uint2((unsigned)dv[i*4+3], (unsigned)s.w);
            }
        }
        __syncthreads();

        for (int idx = tid; idx < nE; idx += 512) {
            uint2 p = stage[idx];
            int b = (int)p.x / NPB;
            slab[(size_t)b * CAP + gbase[b] + (idx - hstart[b])] = p;
        }
        return;
    }

    // ---- gemm role ----
    unsigned short* wl = (unsigned short*)pool;   // 64 KB fragment-ordered W

    const int wave = tid >> 6;
    const int lane = tid & 63;
    const int r  = lane & 15;
    const int kq = lane >> 4;
    const int rowbase = bid * 128 + wave * 16;

    int arow = rowbase + r;
    if (arow >= N_NODES) arow = N_NODES - 1;
    const float4* fr4 = reinterpret_cast<const float4*>(feat + (size_t)arow * IN_F);

    float4 fv[16];
    #pragma unroll
    for (int kt = 0; kt < 8; ++kt) {
        fv[2 * kt]     = fr4[kt * 8 + kq * 2];
        fv[2 * kt + 1] = fr4[kt * 8 + kq * 2 + 1];
    }

    {
        const uint4* wsrc = reinterpret_cast<const uint4*>(Wfrag);
        uint4* wdst = reinterpret_cast<uint4*>(wl);
        #pragma unroll
        for (int i = 0; i < 8; ++i) wdst[tid + i * 512] = wsrc[tid + i * 512];
    }

    bf16x8 a[8];
    #pragma unroll
    for (int kt = 0; kt < 8; ++kt) {
        uint4 au;
        au.x = pack2(fv[2 * kt].x,     fv[2 * kt].y);
        au.y = pack2(fv[2 * kt].z,     fv[2 * kt].w);
        au.z = pack2(fv[2 * kt + 1].x, fv[2 * kt + 1].y);
        au.w = pack2(fv[2 * kt + 1].z, fv[2 * kt + 1].w);
        a[kt] = *reinterpret_cast<bf16x8*>(&au);
    }
    __syncthreads();

    f32x4 acc[8];
    #pragma unroll
    for (int f = 0; f < 8; ++f) acc[f] = (f32x4){0.f, 0.f, 0.f, 0.f};

    #pragma unroll
    for (int kt = 0; kt < 8; ++kt) {
        #pragma unroll
        for (int f = 0; f < 8; ++f) {
            bf16x8 b = *reinterpret_cast<const bf16x8*>(&wl[((f * 8 + kt) * 64 + lane) * 8]);
            acc[f] = __builtin_amdgcn_mfma_f32_16x16x32_bf16(a[kt], b, acc[f], 0, 0, 0);
        }
    }

    // cj scale values for this thread's 4 output rows
    int orow[4]; float cjv[4];
    #pragma unroll
    for (int i = 0; i < 4; ++i) {
        orow[i] = rowbase + kq * 4 + i;
        cjv[i] = cj[orow[i] < N_NODES ? orow[i] : 0];
    }

    // all ds_reads of wl are done; reuse pool as per-wave output staging
    __syncthreads();
    unsigned short* wout = (unsigned short*)pool + wave * (16 * 136);  // 16 rows, stride 136 (pad)
    #pragma unroll
    for (int f = 0; f < 8; ++f) {
        #pragma unroll
        for (int i = 0; i < 4; ++i) {
            wout[(kq * 4 + i) * 136 + f * 16 + r] =
                (unsigned short)f2bf(acc[f][i] * cjv[i]);
        }
    }
    __syncthreads();

    // coalesced store: 4 instructions, each = 16 rows x 64B full lines
    {
        int row = lane >> 2;      // 0..15 within this wave's tile
        int ch  = lane & 3;       // 16B chunk group
        int grow = rowbase + row;
        if (grow < N_NODES) {
            uint4* hv = reinterpret_cast<uint4*>(h);
            #pragma unroll
            for (int j = 0; j < 4; ++j) {
                uint4 vv = *reinterpret_cast<const uint4*>(
                    (const char*)wout + row * 272 + (ch + 4 * j) * 16);
                hv[(size_t)grow * 16 + ch + 4 * j] = vv;
            }
        }
    }
}

// ---------------- scan over 256 bucket sizes -> global bucket bases ----------
__global__ __launch_bounds__(256) void scan256_kernel(const int* __restrict__ bucket_cursor,
                                                      int* __restrict__ bucket_gbase,
                                                      int* __restrict__ offsets) {
    __shared__ int s[256];
    int t = threadIdx.x;
    int v = bucket_cursor[t];
    s[t] = v;
    __syncthreads();
    #pragma unroll
    for (int off = 1; off < 256; off <<= 1) {
        int u = (t >= off) ? s[t - off] : 0;
        __syncthreads();
        s[t] += u;
        __syncthreads();
    }
    bucket_gbase[t] = s[t] - v;
    if (t == 0) offsets[N_NODES] = N_EDGES;
}

// ---------------- bin: per-bucket LDS histogram + scan + rank ----------------
// Computes node offsets[] AND bin_src[] from the slab; no global node atomics.
__global__ __launch_bounds__(256) void bin_kernel(const uint2* __restrict__ slab,
                                                  const int* __restrict__ bucket_cursor,
                                                  const int* __restrict__ bucket_gbase,
                                                  int* __restrict__ offsets,
                                                  int* __restrict__ bin_src) {
    __shared__ int hist[392];
    __shared__ int cur[392];
    __shared__ int sbuf[256];

    const int b = blockIdx.x;
    const int t = threadIdx.x;
    const int nlo = b * NPB;
    int nn = N_NODES - nlo;
    if (nn > NPB) nn = NPB;
    const int sz = bucket_cursor[b];
    const int gb = bucket_gbase[b];
    const uint2* sl = slab + (size_t)b * CAP;

    for (int j = t; j < 392; j += 256) hist[j] = 0;
    __syncthreads();

    for (int i = t; i < sz; i += 256) atomicAdd(&hist[(int)sl[i].x - nlo], 1);
    __syncthreads();

    // scan 392 values: thread t<196 owns (2t, 2t+1)
    int a0 = 0, a1 = 0;
    if (t < 196) { a0 = hist[2 * t]; a1 = hist[2 * t + 1]; }
    int part = a0 + a1;
    sbuf[t] = part;
    __syncthreads();
    #pragma unroll
    for (int off = 1; off < 256; off <<= 1) {
        int u = (t >= off) ? sbuf[t - off] : 0;
        __syncthreads();
        sbuf[t] += u;
        __syncthreads();
    }
    int ex = sbuf[t] - part;
    if (t < 196) {
        int o0 = gb + ex;
        int o1 = o0 + a0;
        if (2 * t < nn)     { offsets[nlo + 2 * t]     = o0; cur[2 * t]     = o0; }
        if (2 * t + 1 < nn) { offsets[nlo + 2 * t + 1] = o1; cur[2 * t + 1] = o1; }
    }
    __syncthreads();

    for (int i = t; i < sz; i += 256) {
        uint2 p = sl[i];
        int pos = atomicAdd(&cur[(int)p.x - nlo], 1);
        bin_src[pos] = (int)p.y;
    }
}

// ---------------- Gather (unchanged) ----------------
__global__ __launch_bounds__(256) void gather_kernel(const unsigned int* __restrict__ h,
                                                     const float* __restrict__ ci,
                                                     const int* __restrict__ offsets,
                                                     const int* __restrict__ bin_src,
                                                     float* __restrict__ out) {
    int node = blockIdx.x * 8 + (threadIdx.x >> 5);
    int lane = threadIdx.x & 31;
    if (node >= N_NODES) return;

    int beg = offsets[node];
    int end = offsets[node + 1];
    const uint2* h2 = reinterpret_cast<const uint2*>(h);

    float4 acc = make_float4(0, 0, 0, 0);
    int i = beg;
    for (; i + 4 <= end; i += 4) {
        int s0 = bin_src[i + 0];
        int s1 = bin_src[i + 1];
        int s2 = bin_src[i + 2];
        int s3 = bin_src[i + 3];
        uint2 v0 = h2[(size_t)s0 * 32 + lane];
        uint2 v1 = h2[(size_t)s1 * 32 + lane];
        uint2 v2 = h2[(size_t)s2 * 32 + lane];
        uint2 v3 = h2[(size_t)s3 * 32 + lane];
        acc.x += (bf_lo(v0.x) + bf_lo(v1.x)) + (bf_lo(v2.x) + bf_lo(v3.x));
        acc.y += (bf_hi(v0.x) + bf_hi(v1.x)) + (bf_hi(v2.x) + bf_hi(v3.x));
        acc.z += (bf_lo(v0.y) + bf_lo(v1.y)) + (bf_lo(v2.y) + bf_lo(v3.y));
        acc.w += (bf_hi(v0.y) + bf_hi(v1.y)) + (bf_hi(v2.y) + bf_hi(v3.y));
    }
    for (; i < end; ++i) {
        int s = bin_src[i];
        uint2 v = h2[(size_t)s * 32 + lane];
        acc.x += bf_lo(v.x);
        acc.y += bf_hi(v.x);
        acc.z += bf_lo(v.y);
        acc.w += bf_hi(v.y);
    }
    float sc = ci[node];
    acc.x *= sc; acc.y *= sc; acc.z *= sc; acc.w *= sc;
    reinterpret_cast<float4*>(out)[(size_t)node * 32 + lane] = acc;
}

extern "C" void kernel_launch(void* const* d_in, const int* in_sizes, int n_in,
                              void* d_out, int out_size, void* d_ws, size_t ws_size,
                              hipStream_t stream) {
    const float* feat = (const float*)d_in[0];
    const float* W    = (const float*)d_in[1];
    const float* cj   = (const float*)d_in[2];
    const float* ci   = (const float*)d_in[3];
    const int*   src  = (const int*)d_in[4];
    const int*   dst  = (const int*)d_in[5];
    float* out = (float*)d_out;

    const size_t H_BYTES   = (size_t)N_NODES * OUT_F * 2;              // 25.6 MB
    const size_t WT_BYTES  = (size_t)IN_F * OUT_F * 2;                 // 64 KB
    const size_t OFF_BYTES = (((size_t)(N_NODES + 1) * 4) + 15) & ~(size_t)15;
    const size_t BC_BYTES  = (size_t)BUCKETS * 4;                      // 1 KB
    const size_t BG_BYTES  = (((size_t)BUCKETS * 4) + 15) & ~(size_t)15;
    const size_t SLAB_BYTES = (size_t)BUCKETS * CAP * 8;               // 16.8 MB

    char* ws = (char*)d_ws;
    unsigned short* h     = (unsigned short*)ws;  ws += H_BYTES;
    unsigned short* Wfrag = (unsigned short*)ws;  ws += WT_BYTES;
    int* offsets        = (int*)ws;   ws += OFF_BYTES;
    int* bucket_cursor  = (int*)ws;   ws += BC_BYTES;
    int* bucket_gbase   = (int*)ws;   ws += BG_BYTES;
    uint2* slab         = (uint2*)ws; ws += SLAB_BYTES;
    int* bin_src        = (int*)ws;

    wprep_kernel<<<128, 256, 0, stream>>>(W, Wfrag);
    hipMemsetAsync(bucket_cursor, 0, BC_BYTES, stream);

    gemm_part_kernel<<<GP_BLOCKS, 512, 0, stream>>>(feat, Wfrag, cj, h, src, dst,
                                                    bucket_cursor, slab);

    scan256_kernel<<<1, 256, 0, stream>>>(bucket_cursor, bucket_gbase, offsets);
    bin_kernel<<<BUCKETS, 256, 0, stream>>>(slab, bucket_cursor, bucket_gbase, offsets, bin_src);

    gather_kernel<<<(N_NODES + 7) / 8, 256, 0, stream>>>((const unsigned int*)h, ci, offsets, bin_src, out);
}

// Round 11
// 126.361 us; speedup vs baseline: 3.2786x; 1.0102x over previous
//
#include <hip/hip_runtime.h>

#define N_NODES 100000
#define N_EDGES 1600000
#define IN_F 256
#define OUT_F 128
#define E4 (N_EDGES / 4)

#define BUCKETS 256
#define NPB 391                        // 256*391 = 100096 >= N_NODES
#define CH 4096
#define NCHUNK ((N_EDGES + CH - 1) / CH)   // 391
#define CAP 8192                       // slab capacity/bucket (mean 6250, +24 sd)

#define GEMM_BLOCKS ((N_NODES + 127) / 128)  // 782 (128 rows/block, 8 waves)
#define GP_BLOCKS (GEMM_BLOCKS + NCHUNK)     // 1173

typedef short bf16x8 __attribute__((ext_vector_type(8)));
typedef float f32x4 __attribute__((ext_vector_type(4)));

// ---- bf16 helpers (RNE) ----
__device__ __forceinline__ unsigned int f2bf(float f) {
    unsigned int u = __float_as_uint(f);
    return (u + 0x7FFFu + ((u >> 16) & 1u)) >> 16;
}
__device__ __forceinline__ unsigned int pack2(float a, float b) {
    return f2bf(a) | (f2bf(b) << 16);
}
__device__ __forceinline__ float bf_lo(unsigned int u) { return __uint_as_float(u << 16); }
__device__ __forceinline__ float bf_hi(unsigned int u) { return __uint_as_float(u & 0xFFFF0000u); }

// ---------------- W prep: fragment-ordered bf16 Wfrag -------------------------
__global__ __launch_bounds__(256) void wprep_kernel(const float* __restrict__ W,
                                                    unsigned short* __restrict__ Wfrag) {
    int idx = blockIdx.x * 256 + threadIdx.x;
    if (idx < IN_F * OUT_F) {
        int j    = idx & 7;
        int lane = (idx >> 3) & 63;
        int fkt  = idx >> 9;
        int f    = fkt >> 3;
        int kt   = fkt & 7;
        int c    = f * 16 + (lane & 15);
        int k    = kt * 32 + (lane >> 4) * 8 + j;
        Wfrag[idx] = (unsigned short)f2bf(W[k * OUT_F + c]);
    }
}

// ---------------- Fused: MFMA gemm + LDS-staged bucket partition --------------
__global__ __launch_bounds__(512) void gemm_part_kernel(const float* __restrict__ feat,
                                                        const unsigned short* __restrict__ Wfrag,
                                                        const float* __restrict__ cj,
                                                        unsigned short* __restrict__ h,
                                                        const int* __restrict__ src,
                                                        const int* __restrict__ dst,
                                                        int* __restrict__ bucket_cursor,
                                                        uint2* __restrict__ slab) {
    __shared__ __align__(16) char pool[65536];

    const int bid = blockIdx.x;
    const int tid = threadIdx.x;

    if (bid >= GEMM_BLOCKS) {
        // ---- partition role ----
        int* hist   = (int*)pool;
        int* hstart = hist + 256;
        int* gbase  = hstart + 256;
        uint2* stage = (uint2*)(pool + 3072);

        const int cb = bid - GEMM_BLOCKS;
        const int e0 = cb * CH;
        int nE = N_EDGES - e0;
        if (nE > CH) nE = CH;

        if (tid < 256) hist[tid] = 0;
        __syncthreads();

        int dv[8], rk[8];
        const int4* d4 = reinterpret_cast<const int4*>(dst);
        #pragma unroll
        for (int i = 0; i < 2; ++i) {
            int li = tid + i * 512;
            int g4 = (e0 >> 2) + li;
            if (li * 4 < nE && g4 < E4) {
                int4 d = d4[g4];
                dv[i*4+0] = d.x; dv[i*4+1] = d.y; dv[i*4+2] = d.z; dv[i*4+3] = d.w;
                rk[i*4+0] = atomicAdd(&hist[d.x / NPB], 1);
                rk[i*4+1] = atomicAdd(&hist[d.y / NPB], 1);
                rk[i*4+2] = atomicAdd(&hist[d.z / NPB], 1);
                rk[i*4+3] = atomicAdd(&hist[d.w / NPB], 1);
            } else {
                dv[i*4+0] = -1; dv[i*4+1] = -1; dv[i*4+2] = -1; dv[i*4+3] = -1;
            }
        }
        __syncthreads();

        int v = 0;
        if (tid < 256) { v = hist[tid]; hstart[tid] = v; }
        __syncthreads();
        #pragma unroll
        for (int off = 1; off < 256; off <<= 1) {
            int u = 0;
            if (tid < 256 && tid >= off) u = hstart[tid - off];
            __syncthreads();
            if (tid < 256) hstart[tid] += u;
            __syncthreads();
        }
        if (tid < 256) {
            int ex = hstart[tid] - v;
            if (v > 0) gbase[tid] = atomicAdd(&bucket_cursor[tid], v);
            hstart[tid] = ex;
        }
        __syncthreads();

        const int4* s4 = reinterpret_cast<const int4*>(src);
        #pragma unroll
        for (int i = 0; i < 2; ++i) {
            int li = tid + i * 512;
            int g4 = (e0 >> 2) + li;
            if (dv[i*4] >= 0) {
                int4 s = s4[g4];
                stage[hstart[dv[i*4+0] / NPB] + rk[i*4+0]] = make_uint2((unsigned)dv[i*4+0], (unsigned)s.x);
                stage[hstart[dv[i*4+1] / NPB] + rk[i*4+1]] = make_uint2((unsigned)dv[i*4+1], (unsigned)s.y);
                stage[hstart[dv[i*4+2] / NPB] + rk[i*4+2]] = make_uint2((unsigned)dv[i*4+2], (unsigned)s.z);
                stage[hstart[dv[i*4+3] / NPB] + rk[i*4+3]] = make_uint2((unsigned)dv[i*4+3], (unsigned)s.w);
            }
        }
        __syncthreads();

        for (int idx = tid; idx < nE; idx += 512) {
            uint2 p = stage[idx];
            int b = (int)p.x / NPB;
            slab[(size_t)b * CAP + gbase[b] + (idx - hstart[b])] = p;
        }
        return;
    }

    // ---- gemm role ----
    unsigned short* wl = (unsigned short*)pool;

    const int wave = tid >> 6;
    const int lane = tid & 63;
    const int r  = lane & 15;
    const int kq = lane >> 4;
    const int rowbase = bid * 128 + wave * 16;

    int arow = rowbase + r;
    if (arow >= N_NODES) arow = N_NODES - 1;
    const float4* fr4 = reinterpret_cast<const float4*>(feat + (size_t)arow * IN_F);

    float4 fv[16];
    #pragma unroll
    for (int kt = 0; kt < 8; ++kt) {
        fv[2 * kt]     = fr4[kt * 8 + kq * 2];
        fv[2 * kt + 1] = fr4[kt * 8 + kq * 2 + 1];
    }

    {
        const uint4* wsrc = reinterpret_cast<const uint4*>(Wfrag);
        uint4* wdst = reinterpret_cast<uint4*>(wl);
        #pragma unroll
        for (int i = 0; i < 8; ++i) wdst[tid + i * 512] = wsrc[tid + i * 512];
    }

    bf16x8 a[8];
    #pragma unroll
    for (int kt = 0; kt < 8; ++kt) {
        uint4 au;
        au.x = pack2(fv[2 * kt].x,     fv[2 * kt].y);
        au.y = pack2(fv[2 * kt].z,     fv[2 * kt].w);
        au.z = pack2(fv[2 * kt + 1].x, fv[2 * kt + 1].y);
        au.w = pack2(fv[2 * kt + 1].z, fv[2 * kt + 1].w);
        a[kt] = *reinterpret_cast<bf16x8*>(&au);
    }
    __syncthreads();

    f32x4 acc[8];
    #pragma unroll
    for (int f = 0; f < 8; ++f) acc[f] = (f32x4){0.f, 0.f, 0.f, 0.f};

    #pragma unroll
    for (int kt = 0; kt < 8; ++kt) {
        #pragma unroll
        for (int f = 0; f < 8; ++f) {
            bf16x8 b = *reinterpret_cast<const bf16x8*>(&wl[((f * 8 + kt) * 64 + lane) * 8]);
            acc[f] = __builtin_amdgcn_mfma_f32_16x16x32_bf16(a[kt], b, acc[f], 0, 0, 0);
        }
    }

    int orow[4]; float cjv[4];
    #pragma unroll
    for (int i = 0; i < 4; ++i) {
        orow[i] = rowbase + kq * 4 + i;
        cjv[i] = cj[orow[i] < N_NODES ? orow[i] : 0];
    }

    __syncthreads();
    unsigned short* wout = (unsigned short*)pool + wave * (16 * 136);
    #pragma unroll
    for (int f = 0; f < 8; ++f) {
        #pragma unroll
        for (int i = 0; i < 4; ++i) {
            wout[(kq * 4 + i) * 136 + f * 16 + r] =
                (unsigned short)f2bf(acc[f][i] * cjv[i]);
        }
    }
    __syncthreads();

    {
        int row = lane >> 2;
        int ch  = lane & 3;
        int grow = rowbase + row;
        if (grow < N_NODES) {
            uint4* hv = reinterpret_cast<uint4*>(h);
            #pragma unroll
            for (int j = 0; j < 4; ++j) {
                uint4 vv = *reinterpret_cast<const uint4*>(
                    (const char*)wout + row * 272 + (ch + 4 * j) * 16);
                hv[(size_t)grow * 16 + ch + 4 * j] = vv;
            }
        }
    }
}

// ---------------- scan over 256 bucket sizes ----------------
__global__ __launch_bounds__(256) void scan256_kernel(const int* __restrict__ bucket_cursor,
                                                      int* __restrict__ bucket_gbase,
                                                      int* __restrict__ offsets) {
    __shared__ int s[256];
    int t = threadIdx.x;
    int v = bucket_cursor[t];
    s[t] = v;
    __syncthreads();
    #pragma unroll
    for (int off = 1; off < 256; off <<= 1) {
        int u = (t >= off) ? s[t - off] : 0;
        __syncthreads();
        s[t] += u;
        __syncthreads();
    }
    bucket_gbase[t] = s[t] - v;
    if (t == 0) offsets[N_NODES] = N_EDGES;
}

// ---------------- bin: per-bucket LDS histogram + scan + rank ----------------
__global__ __launch_bounds__(256) void bin_kernel(const uint2* __restrict__ slab,
                                                  const int* __restrict__ bucket_cursor,
                                                  const int* __restrict__ bucket_gbase,
                                                  int* __restrict__ offsets,
                                                  int* __restrict__ bin_src) {
    __shared__ int hist[392];
    __shared__ int cur[392];
    __shared__ int sbuf[256];

    const int b = blockIdx.x;
    const int t = threadIdx.x;
    const int nlo = b * NPB;
    int nn = N_NODES - nlo;
    if (nn > NPB) nn = NPB;
    const int sz = bucket_cursor[b];
    const int gb = bucket_gbase[b];
    const uint2* sl = slab + (size_t)b * CAP;

    for (int j = t; j < 392; j += 256) hist[j] = 0;
    __syncthreads();

    for (int i = t; i < sz; i += 256) atomicAdd(&hist[(int)sl[i].x - nlo], 1);
    __syncthreads();

    int a0 = 0, a1 = 0;
    if (t < 196) { a0 = hist[2 * t]; a1 = hist[2 * t + 1]; }
    int part = a0 + a1;
    sbuf[t] = part;
    __syncthreads();
    #pragma unroll
    for (int off = 1; off < 256; off <<= 1) {
        int u = (t >= off) ? sbuf[t - off] : 0;
        __syncthreads();
        sbuf[t] += u;
        __syncthreads();
    }
    int ex = sbuf[t] - part;
    if (t < 196) {
        int o0 = gb + ex;
        int o1 = o0 + a0;
        if (2 * t < nn)     { offsets[nlo + 2 * t]     = o0; cur[2 * t]     = o0; }
        if (2 * t + 1 < nn) { offsets[nlo + 2 * t + 1] = o1; cur[2 * t + 1] = o1; }
    }
    __syncthreads();

    for (int i = t; i < sz; i += 256) {
        uint2 p = sl[i];
        int pos = atomicAdd(&cur[(int)p.x - nlo], 1);
        bin_src[pos] = (int)p.y;
    }
}

// ---------------- Gather: 16 lanes/node, uint4 (8 bf16) per lane --------------
// 4 row-requests in flight per 16-lane group -> 16 per wave (2x r10's MLP).
__global__ __launch_bounds__(256) void gather_kernel(const uint4* __restrict__ h4,
                                                     const float* __restrict__ ci,
                                                     const int* __restrict__ offsets,
                                                     const int* __restrict__ bin_src,
                                                     float* __restrict__ out) {
    int node = blockIdx.x * 16 + (threadIdx.x >> 4);
    int lane = threadIdx.x & 15;
    if (node >= N_NODES) return;

    int beg = offsets[node];
    int end = offsets[node + 1];

    float acc[8] = {};
    int i = beg;
    for (; i + 4 <= end; i += 4) {
        int s0 = bin_src[i + 0];
        int s1 = bin_src[i + 1];
        int s2 = bin_src[i + 2];
        int s3 = bin_src[i + 3];
        uint4 v0 = h4[(size_t)s0 * 16 + lane];
        uint4 v1 = h4[(size_t)s1 * 16 + lane];
        uint4 v2 = h4[(size_t)s2 * 16 + lane];
        uint4 v3 = h4[(size_t)s3 * 16 + lane];
        acc[0] += (bf_lo(v0.x) + bf_lo(v1.x)) + (bf_lo(v2.x) + bf_lo(v3.x));
        acc[1] += (bf_hi(v0.x) + bf_hi(v1.x)) + (bf_hi(v2.x) + bf_hi(v3.x));
        acc[2] += (bf_lo(v0.y) + bf_lo(v1.y)) + (bf_lo(v2.y) + bf_lo(v3.y));
        acc[3] += (bf_hi(v0.y) + bf_hi(v1.y)) + (bf_hi(v2.y) + bf_hi(v3.y));
        acc[4] += (bf_lo(v0.z) + bf_lo(v1.z)) + (bf_lo(v2.z) + bf_lo(v3.z));
        acc[5] += (bf_hi(v0.z) + bf_hi(v1.z)) + (bf_hi(v2.z) + bf_hi(v3.z));
        acc[6] += (bf_lo(v0.w) + bf_lo(v1.w)) + (bf_lo(v2.w) + bf_lo(v3.w));
        acc[7] += (bf_hi(v0.w) + bf_hi(v1.w)) + (bf_hi(v2.w) + bf_hi(v3.w));
    }
    for (; i < end; ++i) {
        int s = bin_src[i];
        uint4 v = h4[(size_t)s * 16 + lane];
        acc[0] += bf_lo(v.x); acc[1] += bf_hi(v.x);
        acc[2] += bf_lo(v.y); acc[3] += bf_hi(v.y);
        acc[4] += bf_lo(v.z); acc[5] += bf_hi(v.z);
        acc[6] += bf_lo(v.w); acc[7] += bf_hi(v.w);
    }
    float sc = ci[node];
    float4 o0 = make_float4(acc[0] * sc, acc[1] * sc, acc[2] * sc, acc[3] * sc);
    float4 o1 = make_float4(acc[4] * sc, acc[5] * sc, acc[6] * sc, acc[7] * sc);
    float4* o4 = reinterpret_cast<float4*>(out) + (size_t)node * 32 + lane * 2;
    o4[0] = o0;
    o4[1] = o1;
}

extern "C" void kernel_launch(void* const* d_in, const int* in_sizes, int n_in,
                              void* d_out, int out_size, void* d_ws, size_t ws_size,
                              hipStream_t stream) {
    const float* feat = (const float*)d_in[0];
    const float* W    = (const float*)d_in[1];
    const float* cj   = (const float*)d_in[2];
    const float* ci   = (const float*)d_in[3];
    const int*   src  = (const int*)d_in[4];
    const int*   dst  = (const int*)d_in[5];
    float* out = (float*)d_out;

    const size_t H_BYTES   = (size_t)N_NODES * OUT_F * 2;
    const size_t WT_BYTES  = (size_t)IN_F * OUT_F * 2;
    const size_t OFF_BYTES = (((size_t)(N_NODES + 1) * 4) + 15) & ~(size_t)15;
    const size_t BC_BYTES  = (size_t)BUCKETS * 4;
    const size_t BG_BYTES  = (((size_t)BUCKETS * 4) + 15) & ~(size_t)15;
    const size_t SLAB_BYTES = (size_t)BUCKETS * CAP * 8;

    char* ws = (char*)d_ws;
    unsigned short* h     = (unsigned short*)ws;  ws += H_BYTES;
    unsigned short* Wfrag = (unsigned short*)ws;  ws += WT_BYTES;
    int* offsets        = (int*)ws;   ws += OFF_BYTES;
    int* bucket_cursor  = (int*)ws;   ws += BC_BYTES;
    int* bucket_gbase   = (int*)ws;   ws += BG_BYTES;
    uint2* slab         = (uint2*)ws; ws += SLAB_BYTES;
    int* bin_src        = (int*)ws;

    wprep_kernel<<<128, 256, 0, stream>>>(W, Wfrag);
    hipMemsetAsync(bucket_cursor, 0, BC_BYTES, stream);

    gemm_part_kernel<<<GP_BLOCKS, 512, 0, stream>>>(feat, Wfrag, cj, h, src, dst,
                                                    bucket_cursor, slab);

    scan256_kernel<<<1, 256, 0, stream>>>(bucket_cursor, bucket_gbase, offsets);
    bin_kernel<<<BUCKETS, 256, 0, stream>>>(slab, bucket_cursor, bucket_gbase, offsets, bin_src);

    gather_kernel<<<(N_NODES + 15) / 16, 256, 0, stream>>>((const uint4*)h, ci, offsets, bin_src, out);
}

// Round 12
// 124.781 us; speedup vs baseline: 3.3201x; 1.0127x over previous
//
#include <hip/hip_runtime.h>

#define N_NODES 100000
#define N_EDGES 1600000
#define IN_F 256
#define OUT_F 128
#define E4 (N_EDGES / 4)

#define BUCKETS 256
#define NPB 391                        // 256*391 = 100096 >= N_NODES
#define CH 4096
#define NCHUNK ((N_EDGES + CH - 1) / CH)   // 391
#define CAP 8192                       // slab capacity/bucket (mean 6250, +24 sd)

#define GEMM_T 4
#define GEMM_BLOCKS 196                // 196 * 512 rows = 100352 >= N_NODES
#define GP_BLOCKS (GEMM_BLOCKS + NCHUNK)   // 587

typedef short bf16x8 __attribute__((ext_vector_type(8)));
typedef float f32x4 __attribute__((ext_vector_type(4)));

// ---- bf16 helpers (RNE) ----
__device__ __forceinline__ unsigned int f2bf(float f) {
    unsigned int u = __float_as_uint(f);
    return (u + 0x7FFFu + ((u >> 16) & 1u)) >> 16;
}
__device__ __forceinline__ unsigned int pack2(float a, float b) {
    return f2bf(a) | (f2bf(b) << 16);
}
__device__ __forceinline__ float bf_lo(unsigned int u) { return __uint_as_float(u << 16); }
__device__ __forceinline__ float bf_hi(unsigned int u) { return __uint_as_float(u & 0xFFFF0000u); }

// ---------------- setup: fragment-ordered bf16 Wfrag + zero bucket cursors ----
__global__ __launch_bounds__(256) void setup_kernel(const float* __restrict__ W,
                                                    unsigned short* __restrict__ Wfrag,
                                                    int* __restrict__ bucket_cursor) {
    int idx = blockIdx.x * 256 + threadIdx.x;
    if (idx < IN_F * OUT_F) {
        int j    = idx & 7;
        int lane = (idx >> 3) & 63;
        int fkt  = idx >> 9;
        int f    = fkt >> 3;
        int kt   = fkt & 7;
        int c    = f * 16 + (lane & 15);
        int k    = kt * 32 + (lane >> 4) * 8 + j;
        Wfrag[idx] = (unsigned short)f2bf(W[k * OUT_F + c]);
    }
    if (blockIdx.x == 0 && threadIdx.x < BUCKETS) bucket_cursor[threadIdx.x] = 0;
}

// ---------------- Fused: tiled MFMA gemm + LDS-staged bucket partition --------
// gemm role (bid < GEMM_BLOCKS): 512 thr = 8 waves; 4 tiles of 128 rows each.
//   Wfrag staged to LDS ONCE; feat burst for tile t+1 issued before tile t's
//   MFMA; per-wave LDS transpose staging (separate region) -> full-line stores.
// partition role: unchanged from r10.
__global__ __launch_bounds__(512) void gemm_part_kernel(const float* __restrict__ feat,
                                                        const unsigned short* __restrict__ Wfrag,
                                                        const float* __restrict__ cj,
                                                        unsigned short* __restrict__ h,
                                                        const int* __restrict__ src,
                                                        const int* __restrict__ dst,
                                                        int* __restrict__ bucket_cursor,
                                                        uint2* __restrict__ slab) {
    __shared__ __align__(16) char pool[65536 + 8 * 16 * 136 * 2];   // 100352 B

    const int bid = blockIdx.x;
    const int tid = threadIdx.x;

    if (bid >= GEMM_BLOCKS) {
        // ---- partition role ----
        int* hist   = (int*)pool;
        int* hstart = hist + 256;
        int* gbase  = hstart + 256;
        uint2* stage = (uint2*)(pool + 3072);

        const int cb = bid - GEMM_BLOCKS;
        const int e0 = cb * CH;
        int nE = N_EDGES - e0;
        if (nE > CH) nE = CH;

        if (tid < 256) hist[tid] = 0;
        __syncthreads();

        int dv[8], rk[8];
        const int4* d4 = reinterpret_cast<const int4*>(dst);
        #pragma unroll
        for (int i = 0; i < 2; ++i) {
            int li = tid + i * 512;
            int g4 = (e0 >> 2) + li;
            if (li * 4 < nE && g4 < E4) {
                int4 d = d4[g4];
                dv[i*4+0] = d.x; dv[i*4+1] = d.y; dv[i*4+2] = d.z; dv[i*4+3] = d.w;
                rk[i*4+0] = atomicAdd(&hist[d.x / NPB], 1);
                rk[i*4+1] = atomicAdd(&hist[d.y / NPB], 1);
                rk[i*4+2] = atomicAdd(&hist[d.z / NPB], 1);
                rk[i*4+3] = atomicAdd(&hist[d.w / NPB], 1);
            } else {
                dv[i*4+0] = -1; dv[i*4+1] = -1; dv[i*4+2] = -1; dv[i*4+3] = -1;
            }
        }
        __syncthreads();

        int v = 0;
        if (tid < 256) { v = hist[tid]; hstart[tid] = v; }
        __syncthreads();
        #pragma unroll
        for (int off = 1; off < 256; off <<= 1) {
            int u = 0;
            if (tid < 256 && tid >= off) u = hstart[tid - off];
            __syncthreads();
            if (tid < 256) hstart[tid] += u;
            __syncthreads();
        }
        if (tid < 256) {
            int ex = hstart[tid] - v;
            if (v > 0) gbase[tid] = atomicAdd(&bucket_cursor[tid], v);
            hstart[tid] = ex;
        }
        __syncthreads();

        const int4* s4 = reinterpret_cast<const int4*>(src);
        #pragma unroll
        for (int i = 0; i < 2; ++i) {
            int li = tid + i * 512;
            int g4 = (e0 >> 2) + li;
            if (dv[i*4] >= 0) {
                int4 s = s4[g4];
                stage[hstart[dv[i*4+0] / NPB] + rk[i*4+0]] = make_uint2((unsigned)dv[i*4+0], (unsigned)s.x);
                stage[hstart[dv[i*4+1] / NPB] + rk[i*4+1]] = make_uint2((unsigned)dv[i*4+1], (unsigned)s.y);
                stage[hstart[dv[i*4+2] / NPB] + rk[i*4+2]] = make_uint2((unsigned)dv[i*4+2], (unsigned)s.z);
                stage[hstart[dv[i*4+3] / NPB] + rk[i*4+3]] = make_uint2((unsigned)dv[i*4+3], (unsigned)s.w);
            }
        }
        __syncthreads();

        for (int idx = tid; idx < nE; idx += 512) {
            uint2 p = stage[idx];
            int b = (int)p.x / NPB;
            slab[(size_t)b * CAP + gbase[b] + (idx - hstart[b])] = p;
        }
        return;
    }

    // ---- gemm role ----
    unsigned short* wl = (unsigned short*)pool;                       // 64 KB
    const int wave = tid >> 6;
    const int lane = tid & 63;
    const int r  = lane & 15;
    const int kq = lane >> 4;
    unsigned short* wout = (unsigned short*)(pool + 65536) + wave * (16 * 136);

    float4 fv[16];
    // prologue: tile 0 feat burst
    {
        int arow = bid * 512 + wave * 16 + r;
        if (arow >= N_NODES) arow = N_NODES - 1;
        const float4* fr4 = reinterpret_cast<const float4*>(feat + (size_t)arow * IN_F);
        #pragma unroll
        for (int kt = 0; kt < 8; ++kt) {
            fv[2 * kt]     = fr4[kt * 8 + kq * 2];
            fv[2 * kt + 1] = fr4[kt * 8 + kq * 2 + 1];
        }
    }

    // stage Wfrag -> LDS once
    {
        const uint4* wsrc = reinterpret_cast<const uint4*>(Wfrag);
        uint4* wdst = reinterpret_cast<uint4*>(wl);
        #pragma unroll
        for (int i = 0; i < 8; ++i) wdst[tid + i * 512] = wsrc[tid + i * 512];
    }
    __syncthreads();

    for (int t = 0; t < GEMM_T; ++t) {
        const int rowbase = bid * 512 + t * 128 + wave * 16;

        // pack current feat into a-frags (waits on the in-flight burst)
        bf16x8 a[8];
        #pragma unroll
        for (int kt = 0; kt < 8; ++kt) {
            uint4 au;
            au.x = pack2(fv[2 * kt].x,     fv[2 * kt].y);
            au.y = pack2(fv[2 * kt].z,     fv[2 * kt].w);
            au.z = pack2(fv[2 * kt + 1].x, fv[2 * kt + 1].y);
            au.w = pack2(fv[2 * kt + 1].z, fv[2 * kt + 1].w);
            a[kt] = *reinterpret_cast<bf16x8*>(&au);
        }

        // issue next tile's feat burst (overlaps MFMA below)
        if (t < GEMM_T - 1) {
            int arow = bid * 512 + (t + 1) * 128 + wave * 16 + r;
            if (arow >= N_NODES) arow = N_NODES - 1;
            const float4* fr4 = reinterpret_cast<const float4*>(feat + (size_t)arow * IN_F);
            #pragma unroll
            for (int kt = 0; kt < 8; ++kt) {
                fv[2 * kt]     = fr4[kt * 8 + kq * 2];
                fv[2 * kt + 1] = fr4[kt * 8 + kq * 2 + 1];
            }
        }

        f32x4 acc[8];
        #pragma unroll
        for (int f = 0; f < 8; ++f) acc[f] = (f32x4){0.f, 0.f, 0.f, 0.f};

        #pragma unroll
        for (int kt = 0; kt < 8; ++kt) {
            #pragma unroll
            for (int f = 0; f < 8; ++f) {
                bf16x8 b = *reinterpret_cast<const bf16x8*>(&wl[((f * 8 + kt) * 64 + lane) * 8]);
                acc[f] = __builtin_amdgcn_mfma_f32_16x16x32_bf16(a[kt], b, acc[f], 0, 0, 0);
            }
        }

        int orow[4]; float cjv[4];
        #pragma unroll
        for (int i = 0; i < 4; ++i) {
            orow[i] = rowbase + kq * 4 + i;
            cjv[i] = cj[orow[i] < N_NODES ? orow[i] : 0];
        }

        #pragma unroll
        for (int f = 0; f < 8; ++f) {
            #pragma unroll
            for (int i = 0; i < 4; ++i) {
                wout[(kq * 4 + i) * 136 + f * 16 + r] =
                    (unsigned short)f2bf(acc[f][i] * cjv[i]);
            }
        }
        __syncthreads();   // wout cross-lane transpose visibility

        {
            int row = lane >> 2;
            int ch  = lane & 3;
            int grow = rowbase + row;
            if (grow < N_NODES) {
                uint4* hv = reinterpret_cast<uint4*>(h);
                #pragma unroll
                for (int j = 0; j < 4; ++j) {
                    uint4 vv = *reinterpret_cast<const uint4*>(
                        (const char*)wout + row * 272 + (ch + 4 * j) * 16);
                    hv[(size_t)grow * 16 + ch + 4 * j] = vv;
                }
            }
        }
        __syncthreads();   // wout reads done before next tile overwrites
    }
}

// ---------------- bin: per-bucket; self-scans bucket sizes -> bases -----------
__global__ __launch_bounds__(256) void bin_kernel(const uint2* __restrict__ slab,
                                                  const int* __restrict__ bucket_cursor,
                                                  int* __restrict__ offsets,
                                                  int* __restrict__ bin_src) {
    __shared__ int hist[392];
    __shared__ int cur[392];
    __shared__ int sbuf[256];
    __shared__ int gb_sh, sz_sh;

    const int b = blockIdx.x;
    const int t = threadIdx.x;
    const int nlo = b * NPB;
    int nn = N_NODES - nlo;
    if (nn > NPB) nn = NPB;

    // scan the 256 bucket sizes to get this bucket's global base
    int v = bucket_cursor[t];
    sbuf[t] = v;
    __syncthreads();
    #pragma unroll
    for (int off = 1; off < 256; off <<= 1) {
        int u = (t >= off) ? sbuf[t - off] : 0;
        __syncthreads();
        sbuf[t] += u;
        __syncthreads();
    }
    if (t == b) { gb_sh = sbuf[t] - v; sz_sh = v; }
    if (b == 0 && t == 0) offsets[N_NODES] = N_EDGES;
    __syncthreads();
    const int gb = gb_sh;
    const int sz = sz_sh;
    const uint2* sl = slab + (size_t)b * CAP;

    for (int j = t; j < 392; j += 256) hist[j] = 0;
    __syncthreads();

    for (int i = t; i < sz; i += 256) atomicAdd(&hist[(int)sl[i].x - nlo], 1);
    __syncthreads();

    int a0 = 0, a1 = 0;
    if (t < 196) { a0 = hist[2 * t]; a1 = hist[2 * t + 1]; }
    int part = a0 + a1;
    sbuf[t] = part;
    __syncthreads();
    #pragma unroll
    for (int off = 1; off < 256; off <<= 1) {
        int u = (t >= off) ? sbuf[t - off] : 0;
        __syncthreads();
        sbuf[t] += u;
        __syncthreads();
    }
    int ex = sbuf[t] - part;
    if (t < 196) {
        int o0 = gb + ex;
        int o1 = o0 + a0;
        if (2 * t < nn)     { offsets[nlo + 2 * t]     = o0; cur[2 * t]     = o0; }
        if (2 * t + 1 < nn) { offsets[nlo + 2 * t + 1] = o1; cur[2 * t + 1] = o1; }
    }
    __syncthreads();

    for (int i = t; i < sz; i += 256) {
        uint2 p = sl[i];
        int pos = atomicAdd(&cur[(int)p.x - nlo], 1);
        bin_src[pos] = (int)p.y;
    }
}

// ---------------- Gather: 16 lanes/node, uint4 per lane (unchanged) -----------
__global__ __launch_bounds__(256) void gather_kernel(const uint4* __restrict__ h4,
                                                     const float* __restrict__ ci,
                                                     const int* __restrict__ offsets,
                                                     const int* __restrict__ bin_src,
                                                     float* __restrict__ out) {
    int node = blockIdx.x * 16 + (threadIdx.x >> 4);
    int lane = threadIdx.x & 15;
    if (node >= N_NODES) return;

    int beg = offsets[node];
    int end = offsets[node + 1];

    float acc[8] = {};
    int i = beg;
    for (; i + 4 <= end; i += 4) {
        int s0 = bin_src[i + 0];
        int s1 = bin_src[i + 1];
        int s2 = bin_src[i + 2];
        int s3 = bin_src[i + 3];
        uint4 v0 = h4[(size_t)s0 * 16 + lane];
        uint4 v1 = h4[(size_t)s1 * 16 + lane];
        uint4 v2 = h4[(size_t)s2 * 16 + lane];
        uint4 v3 = h4[(size_t)s3 * 16 + lane];
        acc[0] += (bf_lo(v0.x) + bf_lo(v1.x)) + (bf_lo(v2.x) + bf_lo(v3.x));
        acc[1] += (bf_hi(v0.x) + bf_hi(v1.x)) + (bf_hi(v2.x) + bf_hi(v3.x));
        acc[2] += (bf_lo(v0.y) + bf_lo(v1.y)) + (bf_lo(v2.y) + bf_lo(v3.y));
        acc[3] += (bf_hi(v0.y) + bf_hi(v1.y)) + (bf_hi(v2.y) + bf_hi(v3.y));
        acc[4] += (bf_lo(v0.z) + bf_lo(v1.z)) + (bf_lo(v2.z) + bf_lo(v3.z));
        acc[5] += (bf_hi(v0.z) + bf_hi(v1.z)) + (bf_hi(v2.z) + bf_hi(v3.z));
        acc[6] += (bf_lo(v0.w) + bf_lo(v1.w)) + (bf_lo(v2.w) + bf_lo(v3.w));
        acc[7] += (bf_hi(v0.w) + bf_hi(v1.w)) + (bf_hi(v2.w) + bf_hi(v3.w));
    }
    for (; i < end; ++i) {
        int s = bin_src[i];
        uint4 v = h4[(size_t)s * 16 + lane];
        acc[0] += bf_lo(v.x); acc[1] += bf_hi(v.x);
        acc[2] += bf_lo(v.y); acc[3] += bf_hi(v.y);
        acc[4] += bf_lo(v.z); acc[5] += bf_hi(v.z);
        acc[6] += bf_lo(v.w); acc[7] += bf_hi(v.w);
    }
    float sc = ci[node];
    float4 o0 = make_float4(acc[0] * sc, acc[1] * sc, acc[2] * sc, acc[3] * sc);
    float4 o1 = make_float4(acc[4] * sc, acc[5] * sc, acc[6] * sc, acc[7] * sc);
    float4* o4 = reinterpret_cast<float4*>(out) + (size_t)node * 32 + lane * 2;
    o4[0] = o0;
    o4[1] = o1;
}

extern "C" void kernel_launch(void* const* d_in, const int* in_sizes, int n_in,
                              void* d_out, int out_size, void* d_ws, size_t ws_size,
                              hipStream_t stream) {
    const float* feat = (const float*)d_in[0];
    const float* W    = (const float*)d_in[1];
    const float* cj   = (const float*)d_in[2];
    const float* ci   = (const float*)d_in[3];
    const int*   src  = (const int*)d_in[4];
    const int*   dst  = (const int*)d_in[5];
    float* out = (float*)d_out;

    const size_t H_BYTES   = (size_t)N_NODES * OUT_F * 2;
    const size_t WT_BYTES  = (size_t)IN_F * OUT_F * 2;
    const size_t OFF_BYTES = (((size_t)(N_NODES + 1) * 4) + 15) & ~(size_t)15;
    const size_t BC_BYTES  = (((size_t)BUCKETS * 4) + 15) & ~(size_t)15;
    const size_t SLAB_BYTES = (size_t)BUCKETS * CAP * 8;

    char* ws = (char*)d_ws;
    unsigned short* h     = (unsigned short*)ws;  ws += H_BYTES;
    unsigned short* Wfrag = (unsigned short*)ws;  ws += WT_BYTES;
    int* offsets        = (int*)ws;   ws += OFF_BYTES;
    int* bucket_cursor  = (int*)ws;   ws += BC_BYTES;
    uint2* slab         = (uint2*)ws; ws += SLAB_BYTES;
    int* bin_src        = (int*)ws;

    setup_kernel<<<128, 256, 0, stream>>>(W, Wfrag, bucket_cursor);

    gemm_part_kernel<<<GP_BLOCKS, 512, 0, stream>>>(feat, Wfrag, cj, h, src, dst,
                                                    bucket_cursor, slab);

    bin_kernel<<<BUCKETS, 256, 0, stream>>>(slab, bucket_cursor, offsets, bin_src);

    gather_kernel<<<(N_NODES + 15) / 16, 256, 0, stream>>>((const uint4*)h, ci, offsets, bin_src, out);
}

// Round 13
// 123.565 us; speedup vs baseline: 3.3528x; 1.0098x over previous
//
#include <hip/hip_runtime.h>

#define N_NODES 100000
#define N_EDGES 1600000
#define IN_F 256
#define OUT_F 128
#define E4 (N_EDGES / 4)

#define BUCKETS 256
#define NPB 391                        // 256*391 = 100096 >= N_NODES
#define CH 8192
#define NCHUNK ((N_EDGES + CH - 1) / CH)   // 196
#define CAP 8192                       // slab capacity/bucket (mean 6250, +24 sd)

#define GEMM_T 4
#define GEMM_BLOCKS 196                // 196 * 512 rows = 100352 >= N_NODES
#define GB_BLOCKS (GEMM_BLOCKS + BUCKETS)  // 452: gemm bids 0..195, bin 196..451

typedef short bf16x8 __attribute__((ext_vector_type(8)));
typedef float f32x4 __attribute__((ext_vector_type(4)));

// ---- bf16 helpers (RNE) ----
__device__ __forceinline__ unsigned int f2bf(float f) {
    unsigned int u = __float_as_uint(f);
    return (u + 0x7FFFu + ((u >> 16) & 1u)) >> 16;
}
__device__ __forceinline__ unsigned int pack2(float a, float b) {
    return f2bf(a) | (f2bf(b) << 16);
}
__device__ __forceinline__ float bf_lo(unsigned int u) { return __uint_as_float(u << 16); }
__device__ __forceinline__ float bf_hi(unsigned int u) { return __uint_as_float(u & 0xFFFF0000u); }

// ---------------- P1: partition (+Wfrag prep folded into first 64 blocks) -----
// 196 blocks x 512 thr, 8192 edges/chunk. LDS histogram over 256 buckets ->
// scan -> LDS reorder -> 1 global atomic per (block,bucket) -> burst copy.
__global__ __launch_bounds__(512) void part_kernel(const float* __restrict__ W,
                                                   unsigned short* __restrict__ Wfrag,
                                                   const int* __restrict__ src,
                                                   const int* __restrict__ dst,
                                                   int* __restrict__ bucket_cursor,
                                                   uint2* __restrict__ slab) {
    __shared__ int hist[256];
    __shared__ int hstart[256];
    __shared__ int gbase[256];
    __shared__ uint2 stage[CH];        // 64 KB

    const int bid = blockIdx.x;
    const int t = threadIdx.x;

    // Wfrag prep: fragment-ordered bf16 W (64 blocks x 512 entries = 32768)
    if (bid < 64) {
        int idx = bid * 512 + t;
        int j    = idx & 7;
        int lane = (idx >> 3) & 63;
        int fkt  = idx >> 9;
        int f    = fkt >> 3;
        int kt   = fkt & 7;
        int c    = f * 16 + (lane & 15);
        int k    = kt * 32 + (lane >> 4) * 8 + j;
        Wfrag[idx] = (unsigned short)f2bf(W[k * OUT_F + c]);
    }

    const int e0 = bid * CH;
    int nE = N_EDGES - e0;
    if (nE > CH) nE = CH;

    if (t < 256) hist[t] = 0;
    __syncthreads();

    int dv[16], rk[16];
    const int4* d4 = reinterpret_cast<const int4*>(dst);
    #pragma unroll
    for (int i = 0; i < 4; ++i) {
        int li = t + i * 512;
        int g4 = (e0 >> 2) + li;
        if (li * 4 < nE && g4 < E4) {
            int4 d = d4[g4];
            dv[i*4+0] = d.x; dv[i*4+1] = d.y; dv[i*4+2] = d.z; dv[i*4+3] = d.w;
            rk[i*4+0] = atomicAdd(&hist[d.x / NPB], 1);
            rk[i*4+1] = atomicAdd(&hist[d.y / NPB], 1);
            rk[i*4+2] = atomicAdd(&hist[d.z / NPB], 1);
            rk[i*4+3] = atomicAdd(&hist[d.w / NPB], 1);
        } else {
            dv[i*4+0] = -1; dv[i*4+1] = -1; dv[i*4+2] = -1; dv[i*4+3] = -1;
        }
    }
    __syncthreads();

    int v = 0;
    if (t < 256) { v = hist[t]; hstart[t] = v; }
    __syncthreads();
    #pragma unroll
    for (int off = 1; off < 256; off <<= 1) {
        int u = 0;
        if (t < 256 && t >= off) u = hstart[t - off];
        __syncthreads();
        if (t < 256) hstart[t] += u;
        __syncthreads();
    }
    if (t < 256) {
        int ex = hstart[t] - v;
        if (v > 0) gbase[t] = atomicAdd(&bucket_cursor[t], v);
        hstart[t] = ex;
    }
    __syncthreads();

    const int4* s4 = reinterpret_cast<const int4*>(src);
    #pragma unroll
    for (int i = 0; i < 4; ++i) {
        int li = t + i * 512;
        int g4 = (e0 >> 2) + li;
        if (dv[i*4] >= 0) {
            int4 s = s4[g4];
            stage[hstart[dv[i*4+0] / NPB] + rk[i*4+0]] = make_uint2((unsigned)dv[i*4+0], (unsigned)s.x);
            stage[hstart[dv[i*4+1] / NPB] + rk[i*4+1]] = make_uint2((unsigned)dv[i*4+1], (unsigned)s.y);
            stage[hstart[dv[i*4+2] / NPB] + rk[i*4+2]] = make_uint2((unsigned)dv[i*4+2], (unsigned)s.z);
            stage[hstart[dv[i*4+3] / NPB] + rk[i*4+3]] = make_uint2((unsigned)dv[i*4+3], (unsigned)s.w);
        }
    }
    __syncthreads();

    for (int idx = t; idx < nE; idx += 512) {
        uint2 p = stage[idx];
        int b = (int)p.x / NPB;
        slab[(size_t)b * CAP + gbase[b] + (idx - hstart[b])] = p;
    }
}

// ---------------- Fused: tiled MFMA gemm (bids 0..195) + bin (bids 196..451) --
// gemm role: 8 waves, 4 tiles of 128 rows; Wfrag staged once; feat pipelined;
//   LDS transpose epilogue -> full-line h stores.
// bin role: per-bucket; self-scans bucket sizes; LDS hist+scan -> offsets,
//   LDS-rank -> bin_src. 512-thread variant, all-thread barriers.
__global__ __launch_bounds__(512) void gemm_bin_kernel(const float* __restrict__ feat,
                                                       const unsigned short* __restrict__ Wfrag,
                                                       const float* __restrict__ cj,
                                                       unsigned short* __restrict__ h,
                                                       const uint2* __restrict__ slab,
                                                       const int* __restrict__ bucket_cursor,
                                                       int* __restrict__ offsets,
                                                       int* __restrict__ bin_src) {
    __shared__ __align__(16) char pool[65536 + 8 * 16 * 136 * 2];   // 100352 B

    const int bid = blockIdx.x;
    const int tid = threadIdx.x;

    if (bid >= GEMM_BLOCKS) {
        // ---- bin role ----
        int* hist = (int*)pool;            // 392
        int* cur  = hist + 392;            // 392
        int* sbuf = cur + 392;             // 512
        int* gbsz = sbuf + 512;            // 2

        const int b = bid - GEMM_BLOCKS;
        const int nlo = b * NPB;
        int nn = N_NODES - nlo;
        if (nn > NPB) nn = NPB;

        // scan 256 bucket sizes for this bucket's global base
        int v = (tid < 256) ? bucket_cursor[tid] : 0;
        sbuf[tid] = v;
        __syncthreads();
        #pragma unroll
        for (int off = 1; off < 512; off <<= 1) {
            int u = (tid >= off) ? sbuf[tid - off] : 0;
            __syncthreads();
            sbuf[tid] += u;
            __syncthreads();
        }
        if (tid == b) { gbsz[0] = sbuf[tid] - v; gbsz[1] = v; }
        if (b == 0 && tid == 0) offsets[N_NODES] = N_EDGES;
        __syncthreads();
        const int gb = gbsz[0];
        const int sz = gbsz[1];
        const uint2* sl = slab + (size_t)b * CAP;

        for (int j = tid; j < 392; j += 512) hist[j] = 0;
        __syncthreads();

        for (int i = tid; i < sz; i += 512) atomicAdd(&hist[(int)sl[i].x - nlo], 1);
        __syncthreads();

        // scan 391 node counts (512-wide, zero-padded)
        int hv = (tid < 391) ? hist[tid] : 0;
        sbuf[tid] = hv;
        __syncthreads();
        #pragma unroll
        for (int off = 1; off < 512; off <<= 1) {
            int u = (tid >= off) ? sbuf[tid - off] : 0;
            __syncthreads();
            sbuf[tid] += u;
            __syncthreads();
        }
        if (tid < nn) {
            int o = gb + sbuf[tid] - hv;
            offsets[nlo + tid] = o;
            cur[tid] = o;
        }
        __syncthreads();

        for (int i = tid; i < sz; i += 512) {
            uint2 p = sl[i];
            int pos = atomicAdd(&cur[(int)p.x - nlo], 1);
            bin_src[pos] = (int)p.y;
        }
        return;
    }

    // ---- gemm role ----
    unsigned short* wl = (unsigned short*)pool;                       // 64 KB
    const int wave = tid >> 6;
    const int lane = tid & 63;
    const int r  = lane & 15;
    const int kq = lane >> 4;
    unsigned short* wout = (unsigned short*)(pool + 65536) + wave * (16 * 136);

    float4 fv[16];
    {
        int arow = bid * 512 + wave * 16 + r;
        if (arow >= N_NODES) arow = N_NODES - 1;
        const float4* fr4 = reinterpret_cast<const float4*>(feat + (size_t)arow * IN_F);
        #pragma unroll
        for (int kt = 0; kt < 8; ++kt) {
            fv[2 * kt]     = fr4[kt * 8 + kq * 2];
            fv[2 * kt + 1] = fr4[kt * 8 + kq * 2 + 1];
        }
    }

    {
        const uint4* wsrc = reinterpret_cast<const uint4*>(Wfrag);
        uint4* wdst = reinterpret_cast<uint4*>(wl);
        #pragma unroll
        for (int i = 0; i < 8; ++i) wdst[tid + i * 512] = wsrc[tid + i * 512];
    }
    __syncthreads();

    for (int t = 0; t < GEMM_T; ++t) {
        const int rowbase = bid * 512 + t * 128 + wave * 16;

        bf16x8 a[8];
        #pragma unroll
        for (int kt = 0; kt < 8; ++kt) {
            uint4 au;
            au.x = pack2(fv[2 * kt].x,     fv[2 * kt].y);
            au.y = pack2(fv[2 * kt].z,     fv[2 * kt].w);
            au.z = pack2(fv[2 * kt + 1].x, fv[2 * kt + 1].y);
            au.w = pack2(fv[2 * kt + 1].z, fv[2 * kt + 1].w);
            a[kt] = *reinterpret_cast<bf16x8*>(&au);
        }

        if (t < GEMM_T - 1) {
            int arow = bid * 512 + (t + 1) * 128 + wave * 16 + r;
            if (arow >= N_NODES) arow = N_NODES - 1;
            const float4* fr4 = reinterpret_cast<const float4*>(feat + (size_t)arow * IN_F);
            #pragma unroll
            for (int kt = 0; kt < 8; ++kt) {
                fv[2 * kt]     = fr4[kt * 8 + kq * 2];
                fv[2 * kt + 1] = fr4[kt * 8 + kq * 2 + 1];
            }
        }

        f32x4 acc[8];
        #pragma unroll
        for (int f = 0; f < 8; ++f) acc[f] = (f32x4){0.f, 0.f, 0.f, 0.f};

        #pragma unroll
        for (int kt = 0; kt < 8; ++kt) {
            #pragma unroll
            for (int f = 0; f < 8; ++f) {
                bf16x8 b = *reinterpret_cast<const bf16x8*>(&wl[((f * 8 + kt) * 64 + lane) * 8]);
                acc[f] = __builtin_amdgcn_mfma_f32_16x16x32_bf16(a[kt], b, acc[f], 0, 0, 0);
            }
        }

        int orow[4]; float cjv[4];
        #pragma unroll
        for (int i = 0; i < 4; ++i) {
            orow[i] = rowbase + kq * 4 + i;
            cjv[i] = cj[orow[i] < N_NODES ? orow[i] : 0];
        }

        #pragma unroll
        for (int f = 0; f < 8; ++f) {
            #pragma unroll
            for (int i = 0; i < 4; ++i) {
                wout[(kq * 4 + i) * 136 + f * 16 + r] =
                    (unsigned short)f2bf(acc[f][i] * cjv[i]);
            }
        }
        __syncthreads();

        {
            int row = lane >> 2;
            int ch  = lane & 3;
            int grow = rowbase + row;
            if (grow < N_NODES) {
                uint4* hv = reinterpret_cast<uint4*>(h);
                #pragma unroll
                for (int j = 0; j < 4; ++j) {
                    uint4 vv = *reinterpret_cast<const uint4*>(
                        (const char*)wout + row * 272 + (ch + 4 * j) * 16);
                    hv[(size_t)grow * 16 + ch + 4 * j] = vv;
                }
            }
        }
        __syncthreads();
    }
}

// ---------------- Gather: 16 lanes/node, uint4 per lane (unchanged) -----------
__global__ __launch_bounds__(256) void gather_kernel(const uint4* __restrict__ h4,
                                                     const float* __restrict__ ci,
                                                     const int* __restrict__ offsets,
                                                     const int* __restrict__ bin_src,
                                                     float* __restrict__ out) {
    int node = blockIdx.x * 16 + (threadIdx.x >> 4);
    int lane = threadIdx.x & 15;
    if (node >= N_NODES) return;

    int beg = offsets[node];
    int end = offsets[node + 1];

    float acc[8] = {};
    int i = beg;
    for (; i + 4 <= end; i += 4) {
        int s0 = bin_src[i + 0];
        int s1 = bin_src[i + 1];
        int s2 = bin_src[i + 2];
        int s3 = bin_src[i + 3];
        uint4 v0 = h4[(size_t)s0 * 16 + lane];
        uint4 v1 = h4[(size_t)s1 * 16 + lane];
        uint4 v2 = h4[(size_t)s2 * 16 + lane];
        uint4 v3 = h4[(size_t)s3 * 16 + lane];
        acc[0] += (bf_lo(v0.x) + bf_lo(v1.x)) + (bf_lo(v2.x) + bf_lo(v3.x));
        acc[1] += (bf_hi(v0.x) + bf_hi(v1.x)) + (bf_hi(v2.x) + bf_hi(v3.x));
        acc[2] += (bf_lo(v0.y) + bf_lo(v1.y)) + (bf_lo(v2.y) + bf_lo(v3.y));
        acc[3] += (bf_hi(v0.y) + bf_hi(v1.y)) + (bf_hi(v2.y) + bf_hi(v3.y));
        acc[4] += (bf_lo(v0.z) + bf_lo(v1.z)) + (bf_lo(v2.z) + bf_lo(v3.z));
        acc[5] += (bf_hi(v0.z) + bf_hi(v1.z)) + (bf_hi(v2.z) + bf_hi(v3.z));
        acc[6] += (bf_lo(v0.w) + bf_lo(v1.w)) + (bf_lo(v2.w) + bf_lo(v3.w));
        acc[7] += (bf_hi(v0.w) + bf_hi(v1.w)) + (bf_hi(v2.w) + bf_hi(v3.w));
    }
    for (; i < end; ++i) {
        int s = bin_src[i];
        uint4 v = h4[(size_t)s * 16 + lane];
        acc[0] += bf_lo(v.x); acc[1] += bf_hi(v.x);
        acc[2] += bf_lo(v.y); acc[3] += bf_hi(v.y);
        acc[4] += bf_lo(v.z); acc[5] += bf_hi(v.z);
        acc[6] += bf_lo(v.w); acc[7] += bf_hi(v.w);
    }
    float sc = ci[node];
    float4 o0 = make_float4(acc[0] * sc, acc[1] * sc, acc[2] * sc, acc[3] * sc);
    float4 o1 = make_float4(acc[4] * sc, acc[5] * sc, acc[6] * sc, acc[7] * sc);
    float4* o4 = reinterpret_cast<float4*>(out) + (size_t)node * 32 + lane * 2;
    o4[0] = o0;
    o4[1] = o1;
}

extern "C" void kernel_launch(void* const* d_in, const int* in_sizes, int n_in,
                              void* d_out, int out_size, void* d_ws, size_t ws_size,
                              hipStream_t stream) {
    const float* feat = (const float*)d_in[0];
    const float* W    = (const float*)d_in[1];
    const float* cj   = (const float*)d_in[2];
    const float* ci   = (const float*)d_in[3];
    const int*   src  = (const int*)d_in[4];
    const int*   dst  = (const int*)d_in[5];
    float* out = (float*)d_out;

    const size_t H_BYTES   = (size_t)N_NODES * OUT_F * 2;
    const size_t WT_BYTES  = (size_t)IN_F * OUT_F * 2;
    const size_t OFF_BYTES = (((size_t)(N_NODES + 1) * 4) + 15) & ~(size_t)15;
    const size_t BC_BYTES  = (((size_t)BUCKETS * 4) + 15) & ~(size_t)15;
    const size_t SLAB_BYTES = (size_t)BUCKETS * CAP * 8;

    char* ws = (char*)d_ws;
    unsigned short* h     = (unsigned short*)ws;  ws += H_BYTES;
    unsigned short* Wfrag = (unsigned short*)ws;  ws += WT_BYTES;
    int* offsets        = (int*)ws;   ws += OFF_BYTES;
    int* bucket_cursor  = (int*)ws;   ws += BC_BYTES;
    uint2* slab         = (uint2*)ws; ws += SLAB_BYTES;
    int* bin_src        = (int*)ws;

    hipMemsetAsync(bucket_cursor, 0, (size_t)BUCKETS * 4, stream);

    part_kernel<<<NCHUNK, 512, 0, stream>>>(W, Wfrag, src, dst, bucket_cursor, slab);

    gemm_bin_kernel<<<GB_BLOCKS, 512, 0, stream>>>(feat, Wfrag, cj, h, slab,
                                                   bucket_cursor, offsets, bin_src);

    gather_kernel<<<(N_NODES + 15) / 16, 256, 0, stream>>>((const uint4*)h, ci, offsets, bin_src, out);
}